// Round 1
// baseline (6599.359 us; speedup 1.0000x reference)
//
#include <hip/hip_runtime.h>
#include <hip/hip_bf16.h>

#define N_NODES 65536
#define N_EDGES 393216
#define NB 8
#define HID 128
#define TW 25
#define LAYERS 6
#define BGRAPH 8
#define EPSF 1e-5f
#define TILE_E 64

__device__ __forceinline__ float swishf(float x) {
    return x / (1.0f + __expf(-x));
}

// ---------------------------------------------------------------- gcount
__global__ void gcount_kernel(const int* __restrict__ batch, float* __restrict__ gcount) {
    int b = threadIdx.x;
    if (b >= BGRAPH) return;
    // lower_bound over sorted batch
    auto lb = [&](int key) {
        int lo = 0, hi = N_NODES;
        while (lo < hi) { int mid = (lo + hi) >> 1; if (batch[mid] < key) lo = mid + 1; else hi = mid; }
        return lo;
    };
    int c = lb(b + 1) - lb(b);
    gcount[b] = c > 0 ? (float)c : 1.0f;
}

// ---------------------------------------------------------------- deg
__global__ void deg_kernel(const int* __restrict__ ei, float* __restrict__ deg) {
    int e = blockIdx.x * 256 + threadIdx.x;
    if (e < N_EDGES) atomicAdd(&deg[ei[N_EDGES + e]], 1.0f);
}

// ---------------------------------------------------------------- embedding MLP: 28 -> 128 -> 128
__global__ __launch_bounds__(128) void emb_kernel(
    const float* __restrict__ u, const float* __restrict__ xpos,
    const float* __restrict__ tpos, const float* __restrict__ vars,
    const float* __restrict__ w1, const float* __restrict__ b1,
    const float* __restrict__ w2, const float* __restrict__ b2,
    float* __restrict__ f)
{
    __shared__ float q[NB][HID + 4];
    const int o = threadIdx.x;
    const int n0 = blockIdx.x * NB;
    float acc[NB];
    const float bias = b1[o];
    #pragma unroll
    for (int i = 0; i < NB; ++i) acc[i] = bias;
    for (int k = 0; k < TW; ++k) {
        float w = w1[k * HID + o];
        #pragma unroll
        for (int i = 0; i < NB; ++i) acc[i] += u[(n0 + i) * TW + k] * w;
    }
    {
        float wp = w1[25 * HID + o], wt = w1[26 * HID + o], wv = w1[27 * HID + o];
        #pragma unroll
        for (int i = 0; i < NB; ++i) {
            int n = n0 + i;
            acc[i] += (xpos[n] * (1.0f / 16.0f)) * wp + (tpos[n] * 0.25f) * wt + vars[n] * wv;
        }
    }
    #pragma unroll
    for (int i = 0; i < NB; ++i) q[i][o] = swishf(acc[i]);
    __syncthreads();
    float acc2[NB];
    const float bias2 = b2[o];
    #pragma unroll
    for (int i = 0; i < NB; ++i) acc2[i] = bias2;
    for (int k = 0; k < HID; ++k) {
        float w = w2[k * HID + o];
        #pragma unroll
        for (int i = 0; i < NB; ++i) acc2[i] += q[i][k] * w;
    }
    #pragma unroll
    for (int i = 0; i < NB; ++i) f[(n0 + i) * HID + o] = swishf(acc2[i]);
}

// ---------------------------------------------------------------- per-layer node precompute A / Bv
// A[n]  = f[n]@W[0:128]   + u[n]@W[256:281] + pos*W[281] + t*W[282] + v*W[283] + b1
// Bv[n] = f[n]@W[128:256] - u[n]@W[256:281] - pos*W[281]
__global__ __launch_bounds__(256) void abv_kernel(
    const float* __restrict__ f, const float* __restrict__ u,
    const float* __restrict__ xpos, const float* __restrict__ tpos,
    const float* __restrict__ vars,
    const float* __restrict__ W, const float* __restrict__ bias1,
    float* __restrict__ A, float* __restrict__ Bv)
{
    const int gid = blockIdx.x * 256 + threadIdx.x;
    const int o = gid & (HID - 1);
    const int g = gid >> 7;
    const int n0 = g * NB;
    float accA[NB] = {}, accB[NB] = {};
    for (int kq = 0; kq < HID / 4; ++kq) {
        float4 fv[NB];
        #pragma unroll
        for (int i = 0; i < NB; ++i)
            fv[i] = *reinterpret_cast<const float4*>(f + (n0 + i) * HID + kq * 4);
        #pragma unroll
        for (int kk = 0; kk < 4; ++kk) {
            int k = kq * 4 + kk;
            float wi = W[k * HID + o];
            float wj = W[(HID + k) * HID + o];
            #pragma unroll
            for (int i = 0; i < NB; ++i) {
                float fvv = reinterpret_cast<const float*>(&fv[i])[kk];
                accA[i] += fvv * wi;
                accB[i] += fvv * wj;
            }
        }
    }
    float c[NB] = {};
    for (int k = 0; k < TW; ++k) {
        float wu = W[(256 + k) * HID + o];
        #pragma unroll
        for (int i = 0; i < NB; ++i) c[i] += u[(n0 + i) * TW + k] * wu;
    }
    const float wp = W[281 * HID + o], wt = W[282 * HID + o], wv = W[283 * HID + o];
    const float bb = bias1[o];
    #pragma unroll
    for (int i = 0; i < NB; ++i) {
        int n = n0 + i;
        float ci = c[i] + (xpos[n] * (1.0f / 16.0f)) * wp;
        A[n * HID + o]  = accA[i] + bb + ci + (tpos[n] * 0.25f) * wt + vars[n] * wv;
        Bv[n * HID + o] = accB[i] - ci;
    }
}

// ---------------------------------------------------------------- fused edge kernel
// t = swish(A[dst] + Bv[src]);  out = swish(t @ W2 + b2);  agg[dst] += out
__global__ __launch_bounds__(256) void edge_kernel(
    const int* __restrict__ ei,
    const float* __restrict__ A, const float* __restrict__ Bv,
    const float* __restrict__ W2, const float* __restrict__ b2,
    float* __restrict__ agg)
{
    __shared__ float t_lds[TILE_E][HID + 4];
    __shared__ int s_src[TILE_E], s_dst[TILE_E];
    const int tid = threadIdx.x;
    const int e0 = blockIdx.x * TILE_E;
    if (tid < TILE_E) {
        s_src[tid] = ei[e0 + tid];
        s_dst[tid] = ei[N_EDGES + e0 + tid];
    }
    __syncthreads();
    // phase 1: gather + swish -> LDS
    #pragma unroll
    for (int i = 0; i < 8; ++i) {
        int qi = tid + i * 256;
        int e = qi >> 5, kq = qi & 31;
        const float4 a4 = *reinterpret_cast<const float4*>(A + s_dst[e] * HID + kq * 4);
        const float4 b4 = *reinterpret_cast<const float4*>(Bv + s_src[e] * HID + kq * 4);
        float4 t4;
        t4.x = swishf(a4.x + b4.x);
        t4.y = swishf(a4.y + b4.y);
        t4.z = swishf(a4.z + b4.z);
        t4.w = swishf(a4.w + b4.w);
        *reinterpret_cast<float4*>(&t_lds[e][kq * 4]) = t4;
    }
    __syncthreads();
    // phase 2: [64,128]@[128,128] GEMM, thread = 4 outs x 8 edges
    const int o0 = (tid & 31) * 4;
    const int eg = tid >> 5;
    float acc[8][4] = {};
    for (int kq = 0; kq < 32; ++kq) {
        float4 w0 = *reinterpret_cast<const float4*>(W2 + (kq * 4 + 0) * HID + o0);
        float4 w1 = *reinterpret_cast<const float4*>(W2 + (kq * 4 + 1) * HID + o0);
        float4 w2 = *reinterpret_cast<const float4*>(W2 + (kq * 4 + 2) * HID + o0);
        float4 w3 = *reinterpret_cast<const float4*>(W2 + (kq * 4 + 3) * HID + o0);
        #pragma unroll
        for (int j = 0; j < 8; ++j) {
            float4 t4 = *reinterpret_cast<const float4*>(&t_lds[eg * 8 + j][kq * 4]);
            acc[j][0] += t4.x * w0.x + t4.y * w1.x + t4.z * w2.x + t4.w * w3.x;
            acc[j][1] += t4.x * w0.y + t4.y * w1.y + t4.z * w2.y + t4.w * w3.y;
            acc[j][2] += t4.x * w0.z + t4.y * w1.z + t4.z * w2.z + t4.w * w3.z;
            acc[j][3] += t4.x * w0.w + t4.y * w1.w + t4.z * w2.w + t4.w * w3.w;
        }
    }
    const float4 bb = *reinterpret_cast<const float4*>(b2 + o0);
    #pragma unroll
    for (int j = 0; j < 8; ++j) {
        int e = eg * 8 + j;
        float* dstp = agg + s_dst[e] * HID + o0;
        atomicAdd(dstp + 0, swishf(acc[j][0] + bb.x));
        atomicAdd(dstp + 1, swishf(acc[j][1] + bb.y));
        atomicAdd(dstp + 2, swishf(acc[j][2] + bb.z));
        atomicAdd(dstp + 3, swishf(acc[j][3] + bb.w));
    }
}

// ---------------------------------------------------------------- update MLP: [f, agg/deg, var_all] 258->128->128, +residual
__global__ __launch_bounds__(128) void update_kernel(
    const float* __restrict__ f, const float* __restrict__ agg,
    const float* __restrict__ deg, const float* __restrict__ tpos,
    const float* __restrict__ vars,
    const float* __restrict__ U1, const float* __restrict__ b1,
    const float* __restrict__ U2, const float* __restrict__ b2,
    float* __restrict__ h)
{
    __shared__ float q[NB][HID + 4];
    const int o = threadIdx.x;
    const int n0 = blockIdx.x * NB;
    float acc[NB];
    float invd[NB];
    const float bias = b1[o];
    #pragma unroll
    for (int i = 0; i < NB; ++i) {
        acc[i] = bias;
        invd[i] = 1.0f / fmaxf(deg[n0 + i], 1.0f);
    }
    for (int kq = 0; kq < 32; ++kq) {
        float4 fv[NB];
        #pragma unroll
        for (int i = 0; i < NB; ++i)
            fv[i] = *reinterpret_cast<const float4*>(f + (n0 + i) * HID + kq * 4);
        #pragma unroll
        for (int kk = 0; kk < 4; ++kk) {
            float w = U1[(kq * 4 + kk) * HID + o];
            #pragma unroll
            for (int i = 0; i < NB; ++i)
                acc[i] += reinterpret_cast<const float*>(&fv[i])[kk] * w;
        }
    }
    for (int kq = 0; kq < 32; ++kq) {
        float4 av[NB];
        #pragma unroll
        for (int i = 0; i < NB; ++i) {
            av[i] = *reinterpret_cast<const float4*>(agg + (n0 + i) * HID + kq * 4);
            av[i].x *= invd[i]; av[i].y *= invd[i]; av[i].z *= invd[i]; av[i].w *= invd[i];
        }
        #pragma unroll
        for (int kk = 0; kk < 4; ++kk) {
            float w = U1[(HID + kq * 4 + kk) * HID + o];
            #pragma unroll
            for (int i = 0; i < NB; ++i)
                acc[i] += reinterpret_cast<const float*>(&av[i])[kk] * w;
        }
    }
    {
        float wt = U1[256 * HID + o], wv = U1[257 * HID + o];
        #pragma unroll
        for (int i = 0; i < NB; ++i) {
            int n = n0 + i;
            acc[i] += (tpos[n] * 0.25f) * wt + vars[n] * wv;
        }
    }
    #pragma unroll
    for (int i = 0; i < NB; ++i) q[i][o] = swishf(acc[i]);
    __syncthreads();
    float acc2[NB];
    const float bias2 = b2[o];
    #pragma unroll
    for (int i = 0; i < NB; ++i) acc2[i] = bias2;
    for (int kq = 0; kq < 32; ++kq) {
        #pragma unroll
        for (int kk = 0; kk < 4; ++kk) {
            float w = U2[(kq * 4 + kk) * HID + o];
            #pragma unroll
            for (int i = 0; i < NB; ++i) acc2[i] += q[i][kq * 4 + kk] * w;
        }
    }
    #pragma unroll
    for (int i = 0; i < NB; ++i)
        h[(n0 + i) * HID + o] = f[(n0 + i) * HID + o] + swishf(acc2[i]);
}

// ---------------------------------------------------------------- instance-norm stats (batch sorted)
__global__ __launch_bounds__(256) void stats_kernel(
    const float* __restrict__ h, const int* __restrict__ batch,
    float* __restrict__ dsum, float* __restrict__ dsq)
{
    const int feat = threadIdx.x & (HID - 1);
    const int sub = threadIdx.x >> 7;
    const int base = blockIdx.x * 64;
    float s = 0.0f, s2 = 0.0f;
    int cur = -1;
    for (int i = 0; i < 32; ++i) {
        int n = base + sub + 2 * i;
        int b = batch[n];
        float v = h[n * HID + feat];
        if (b != cur) {
            if (cur >= 0) {
                atomicAdd(&dsum[cur * HID + feat], s);
                atomicAdd(&dsq[cur * HID + feat], s2);
            }
            cur = b; s = 0.0f; s2 = 0.0f;
        }
        s += v; s2 += v * v;
    }
    if (cur >= 0) {
        atomicAdd(&dsum[cur * HID + feat], s);
        atomicAdd(&dsq[cur * HID + feat], s2);
    }
}

// ---------------------------------------------------------------- normalize
__global__ __launch_bounds__(256) void norm_kernel(
    const float* __restrict__ h, const int* __restrict__ batch,
    const float* __restrict__ dsum, const float* __restrict__ dsq,
    const float* __restrict__ gcount, float* __restrict__ f)
{
    const int gid = blockIdx.x * 256 + threadIdx.x;
    const int n = gid >> 7, feat = gid & (HID - 1);
    const int b = batch[n];
    const float gc = gcount[b];
    const float mean = dsum[b * HID + feat] / gc;
    const float var = dsq[b * HID + feat] / gc - mean * mean;
    f[gid] = (h[gid] - mean) * rsqrtf(var + EPSF);
}

// ---------------------------------------------------------------- conv head
__global__ __launch_bounds__(256) void head_kernel(
    const float* __restrict__ f, const float* __restrict__ u,
    const float* __restrict__ c1w, const float* __restrict__ c1b,
    const float* __restrict__ c2w, const float* __restrict__ c2b,
    float* __restrict__ out)
{
    __shared__ float fs[16][HID];
    __shared__ float y1[16][8][40];
    const int tid = threadIdx.x;
    const int n0 = blockIdx.x * 16;
    #pragma unroll
    for (int i = 0; i < 2; ++i) {
        int qi = tid + i * 256;
        int node = qi >> 5, kq = qi & 31;
        *reinterpret_cast<float4*>(&fs[node][kq * 4]) =
            *reinterpret_cast<const float4*>(f + (n0 + node) * HID + kq * 4);
    }
    __syncthreads();
    {
        const int node = tid >> 4;
        const int rem = tid & 15;
        const int o = rem >> 1;
        const int ph = rem & 1;
        const float cb = c1b[o];
        float wk[16];
        #pragma unroll
        for (int k = 0; k < 16; ++k) wk[k] = c1w[o * 16 + k];
        for (int p = ph * 19; p < ph * 19 + 19; ++p) {
            float acc = cb;
            #pragma unroll
            for (int k = 0; k < 16; ++k) acc += fs[node][p * 3 + k] * wk[k];
            y1[node][o][p] = swishf(acc);
        }
    }
    __syncthreads();
    const float cb2 = c2b[0];
    #pragma unroll
    for (int pass = 0; pass < 2; ++pass) {
        int unit = tid + pass * 256;
        if (unit < 16 * TW) {
            int node = unit / TW, t = unit % TW;
            float acc = cb2;
            #pragma unroll
            for (int o = 0; o < 8; ++o)
                #pragma unroll
                for (int k = 0; k < 14; ++k)
                    acc += y1[node][o][t + k] * c2w[o * 14 + k];
            int n = n0 + node;
            out[n * TW + t] = u[n * TW + (TW - 1)] + (0.016f * (float)(t + 1)) * acc;
        }
    }
}

// ---------------------------------------------------------------- launch
extern "C" void kernel_launch(void* const* d_in, const int* in_sizes, int n_in,
                              void* d_out, int out_size, void* d_ws, size_t ws_size,
                              hipStream_t stream)
{
    (void)in_sizes; (void)n_in; (void)out_size; (void)ws_size;
    const float* u      = (const float*)d_in[0];
    const float* xpos   = (const float*)d_in[1];
    const float* tpos   = (const float*)d_in[2];
    const float* vars   = (const float*)d_in[3];
    const int*   ei     = (const int*)d_in[4];
    const int*   batch  = (const int*)d_in[5];
    const float* emb_w1 = (const float*)d_in[6];
    const float* emb_b1 = (const float*)d_in[7];
    const float* emb_w2 = (const float*)d_in[8];
    const float* emb_b2 = (const float*)d_in[9];
    const float* m1_w   = (const float*)d_in[10];
    const float* m1_b   = (const float*)d_in[11];
    const float* m2_w   = (const float*)d_in[12];
    const float* m2_b   = (const float*)d_in[13];
    const float* u1_w   = (const float*)d_in[14];
    const float* u1_b   = (const float*)d_in[15];
    const float* u2_w   = (const float*)d_in[16];
    const float* u2_b   = (const float*)d_in[17];
    const float* c1w    = (const float*)d_in[18];
    const float* c1b    = (const float*)d_in[19];
    const float* c2w    = (const float*)d_in[20];
    const float* c2b    = (const float*)d_in[21];
    float* out = (float*)d_out;

    char* ws = (char*)d_ws;
    const size_t fbytes = (size_t)N_NODES * HID * sizeof(float);
    float* f      = (float*)(ws);
    float* Ah     = (float*)(ws + fbytes);          // A during message, h during update/norm
    float* Bv     = (float*)(ws + 2 * fbytes);
    float* agg    = (float*)(ws + 3 * fbytes);
    float* deg    = (float*)(ws + 4 * fbytes);
    float* dsum   = (float*)(ws + 4 * fbytes + (size_t)N_NODES * 4);
    float* dsq    = dsum + BGRAPH * HID;
    float* gcount = dsq + BGRAPH * HID;

    hipMemsetAsync(deg, 0, (size_t)N_NODES * 4, stream);
    deg_kernel<<<N_EDGES / 256, 256, 0, stream>>>(ei, deg);
    gcount_kernel<<<1, 64, 0, stream>>>(batch, gcount);
    emb_kernel<<<N_NODES / NB, 128, 0, stream>>>(u, xpos, tpos, vars,
                                                 emb_w1, emb_b1, emb_w2, emb_b2, f);
    for (int l = 0; l < LAYERS; ++l) {
        abv_kernel<<<(N_NODES / NB) * HID / 256, 256, 0, stream>>>(
            f, u, xpos, tpos, vars,
            m1_w + (size_t)l * 284 * HID, m1_b + (size_t)l * HID, Ah, Bv);
        hipMemsetAsync(agg, 0, fbytes, stream);
        edge_kernel<<<N_EDGES / TILE_E, 256, 0, stream>>>(
            ei, Ah, Bv, m2_w + (size_t)l * HID * HID, m2_b + (size_t)l * HID, agg);
        update_kernel<<<N_NODES / NB, 128, 0, stream>>>(
            f, agg, deg, tpos, vars,
            u1_w + (size_t)l * 258 * HID, u1_b + (size_t)l * HID,
            u2_w + (size_t)l * HID * HID, u2_b + (size_t)l * HID, Ah);
        hipMemsetAsync(dsum, 0, (size_t)2 * BGRAPH * HID * 4, stream);
        stats_kernel<<<N_NODES / 64, 256, 0, stream>>>(Ah, batch, dsum, dsq);
        norm_kernel<<<(size_t)N_NODES * HID / 256, 256, 0, stream>>>(
            Ah, batch, dsum, dsq, gcount, f);
    }
    head_kernel<<<N_NODES / 16, 256, 0, stream>>>(f, u, c1w, c1b, c2w, c2b, out);
}

// Round 2
// 3168.677 us; speedup vs baseline: 2.0827x; 2.0827x over previous
//
#include <hip/hip_runtime.h>
#include <hip/hip_bf16.h>

#define N_NODES 65536
#define N_EDGES 393216
#define NB 8
#define HID 128
#define TW 25
#define LAYERS 6
#define BGRAPH 8
#define EPSF 1e-5f
#define TILE_E 128

typedef __attribute__((ext_vector_type(8))) short bf16x8;
typedef __attribute__((ext_vector_type(4))) float f32x4;

__device__ __forceinline__ float swishf(float x) {
    return x / (1.0f + __expf(-x));
}

__device__ __forceinline__ unsigned short f2bf(float x) {
    unsigned int u = __float_as_uint(x);
    u += 0x7fffu + ((u >> 16) & 1u);
    return (unsigned short)(u >> 16);
}

__device__ __forceinline__ unsigned int pack2bf(float lo, float hi) {
    return (unsigned int)f2bf(lo) | ((unsigned int)f2bf(hi) << 16);
}

// ---------------------------------------------------------------- gcount
__global__ void gcount_kernel(const int* __restrict__ batch, float* __restrict__ gcount) {
    int b = threadIdx.x;
    if (b >= BGRAPH) return;
    auto lb = [&](int key) {
        int lo = 0, hi = N_NODES;
        while (lo < hi) { int mid = (lo + hi) >> 1; if (batch[mid] < key) lo = mid + 1; else hi = mid; }
        return lo;
    };
    int c = lb(b + 1) - lb(b);
    gcount[b] = c > 0 ? (float)c : 1.0f;
}

// ---------------------------------------------------------------- CSR build
__global__ void count_kernel(const int* __restrict__ ei, int* __restrict__ cnt) {
    int e = blockIdx.x * 256 + threadIdx.x;
    if (e < N_EDGES) atomicAdd(&cnt[ei[N_EDGES + e]], 1);
}

__global__ __launch_bounds__(256) void block_sum_kernel(const int* __restrict__ cnt, int* __restrict__ bsum) {
    __shared__ int s[256];
    int t = threadIdx.x;
    s[t] = cnt[blockIdx.x * 256 + t];
    __syncthreads();
    for (int st = 128; st > 0; st >>= 1) {
        if (t < st) s[t] += s[t + st];
        __syncthreads();
    }
    if (t == 0) bsum[blockIdx.x] = s[0];
}

__global__ __launch_bounds__(256) void scan_bsum_kernel(const int* __restrict__ bsum, int* __restrict__ bpref) {
    __shared__ int s[256];
    int t = threadIdx.x;
    int orig = bsum[t];
    s[t] = orig;
    __syncthreads();
    for (int st = 1; st < 256; st <<= 1) {
        int v = (t >= st) ? s[t - st] : 0;
        __syncthreads();
        s[t] += v;
        __syncthreads();
    }
    bpref[t] = s[t] - orig;   // exclusive prefix
}

__global__ __launch_bounds__(256) void offsets_kernel(const int* __restrict__ cnt, const int* __restrict__ bpref,
                                                      int* __restrict__ cursor) {
    __shared__ int s[256];
    int t = threadIdx.x;
    int base = blockIdx.x * 256;
    int orig = cnt[base + t];
    s[t] = orig;
    __syncthreads();
    for (int st = 1; st < 256; st <<= 1) {
        int v = (t >= st) ? s[t - st] : 0;
        __syncthreads();
        s[t] += v;
        __syncthreads();
    }
    cursor[base + t] = s[t] - orig + bpref[blockIdx.x];
}

__global__ void scatter_kernel(const int* __restrict__ ei, int* __restrict__ cursor,
                               int* __restrict__ src_s, int* __restrict__ dst_s) {
    int e = blockIdx.x * 256 + threadIdx.x;
    if (e >= N_EDGES) return;
    int d = ei[N_EDGES + e];
    int pos = atomicAdd(&cursor[d], 1);
    src_s[pos] = ei[e];
    dst_s[pos] = d;
}

// ---------------------------------------------------------------- W2 -> bf16 transposed  W2T[l][n][k]
__global__ void w2bf_kernel(const float* __restrict__ m2_w, unsigned short* __restrict__ W2T) {
    int idx = blockIdx.x * 256 + threadIdx.x;   // 6*128*128
    int l = idx >> 14;
    int rem = idx & 16383;
    int n = rem >> 7, k = rem & 127;
    W2T[idx] = f2bf(m2_w[l * 16384 + k * HID + n]);
}

// ---------------------------------------------------------------- embedding MLP: 28 -> 128 -> 128
__global__ __launch_bounds__(128) void emb_kernel(
    const float* __restrict__ u, const float* __restrict__ xpos,
    const float* __restrict__ tpos, const float* __restrict__ vars,
    const float* __restrict__ w1, const float* __restrict__ b1,
    const float* __restrict__ w2, const float* __restrict__ b2,
    float* __restrict__ f)
{
    __shared__ float q[NB][HID + 4];
    const int o = threadIdx.x;
    const int n0 = blockIdx.x * NB;
    float acc[NB];
    const float bias = b1[o];
    #pragma unroll
    for (int i = 0; i < NB; ++i) acc[i] = bias;
    for (int k = 0; k < TW; ++k) {
        float w = w1[k * HID + o];
        #pragma unroll
        for (int i = 0; i < NB; ++i) acc[i] += u[(n0 + i) * TW + k] * w;
    }
    {
        float wp = w1[25 * HID + o], wt = w1[26 * HID + o], wv = w1[27 * HID + o];
        #pragma unroll
        for (int i = 0; i < NB; ++i) {
            int n = n0 + i;
            acc[i] += (xpos[n] * (1.0f / 16.0f)) * wp + (tpos[n] * 0.25f) * wt + vars[n] * wv;
        }
    }
    #pragma unroll
    for (int i = 0; i < NB; ++i) q[i][o] = swishf(acc[i]);
    __syncthreads();
    float acc2[NB];
    const float bias2 = b2[o];
    #pragma unroll
    for (int i = 0; i < NB; ++i) acc2[i] = bias2;
    for (int k = 0; k < HID; ++k) {
        float w = w2[k * HID + o];
        #pragma unroll
        for (int i = 0; i < NB; ++i) acc2[i] += q[i][k] * w;
    }
    #pragma unroll
    for (int i = 0; i < NB; ++i) f[(n0 + i) * HID + o] = swishf(acc2[i]);
}

// ---------------------------------------------------------------- per-layer node precompute A / Bv
__global__ __launch_bounds__(256) void abv_kernel(
    const float* __restrict__ f, const float* __restrict__ u,
    const float* __restrict__ xpos, const float* __restrict__ tpos,
    const float* __restrict__ vars,
    const float* __restrict__ W, const float* __restrict__ bias1,
    float* __restrict__ A, float* __restrict__ Bv)
{
    const int gid = blockIdx.x * 256 + threadIdx.x;
    const int o = gid & (HID - 1);
    const int g = gid >> 7;
    const int n0 = g * NB;
    float accA[NB] = {}, accB[NB] = {};
    for (int kq = 0; kq < HID / 4; ++kq) {
        float4 fv[NB];
        #pragma unroll
        for (int i = 0; i < NB; ++i)
            fv[i] = *reinterpret_cast<const float4*>(f + (n0 + i) * HID + kq * 4);
        #pragma unroll
        for (int kk = 0; kk < 4; ++kk) {
            int k = kq * 4 + kk;
            float wi = W[k * HID + o];
            float wj = W[(HID + k) * HID + o];
            #pragma unroll
            for (int i = 0; i < NB; ++i) {
                float fvv = reinterpret_cast<const float*>(&fv[i])[kk];
                accA[i] += fvv * wi;
                accB[i] += fvv * wj;
            }
        }
    }
    float c[NB] = {};
    for (int k = 0; k < TW; ++k) {
        float wu = W[(256 + k) * HID + o];
        #pragma unroll
        for (int i = 0; i < NB; ++i) c[i] += u[(n0 + i) * TW + k] * wu;
    }
    const float wp = W[281 * HID + o], wt = W[282 * HID + o], wv = W[283 * HID + o];
    const float bb = bias1[o];
    #pragma unroll
    for (int i = 0; i < NB; ++i) {
        int n = n0 + i;
        float ci = c[i] + (xpos[n] * (1.0f / 16.0f)) * wp;
        A[n * HID + o]  = accA[i] + bb + ci + (tpos[n] * 0.25f) * wt + vars[n] * wv;
        Bv[n * HID + o] = accB[i] - ci;
    }
}

// ---------------------------------------------------------------- fused edge kernel (CSR-sorted, MFMA)
// t = swish(A[dst] + Bv[src]) -> bf16 LDS (swizzled); out = swish(t @ W2 + b2); seg-accumulate into agg
__global__ __launch_bounds__(256) void edge_mfma_kernel(
    const int* __restrict__ src_s, const int* __restrict__ dst_s,
    const float* __restrict__ A, const float* __restrict__ Bv,
    const unsigned short* __restrict__ W2T, const float* __restrict__ b2,
    float* __restrict__ agg)
{
    __shared__ unsigned short t_bf[TILE_E * HID];   // 32 KB, XOR-swizzled rows
    __shared__ unsigned short w_bf[HID * HID];      // 32 KB, XOR-swizzled rows (W2T layout [n][k])
    __shared__ int s_src[TILE_E], s_dst[TILE_E];
    const int tid = threadIdx.x;
    const int e0 = blockIdx.x * TILE_E;

    if (tid < TILE_E) {
        s_src[tid] = src_s[e0 + tid];
        s_dst[tid] = dst_s[e0 + tid];
    }
    // stage W2T -> LDS (swizzled): 128 rows x 16 16B-blocks
    #pragma unroll
    for (int i = 0; i < 8; ++i) {
        int un = tid + i * 256;
        int r = un >> 4, cb = un & 15;
        uint4 w = *reinterpret_cast<const uint4*>(W2T + r * HID + cb * 8);
        int byte = r * 256 + ((cb * 16) ^ ((r & 7) << 4));
        *reinterpret_cast<uint4*>(reinterpret_cast<char*>(w_bf) + byte) = w;
    }
    __syncthreads();

    // gather + swish -> bf16 LDS: 128 edges x 16 col-blocks
    #pragma unroll
    for (int i = 0; i < 8; ++i) {
        int un = tid + i * 256;
        int e = un >> 4, cb = un & 15;
        int d = s_dst[e], s = s_src[e];
        const float4 a0 = *reinterpret_cast<const float4*>(A + d * HID + cb * 8);
        const float4 a1 = *reinterpret_cast<const float4*>(A + d * HID + cb * 8 + 4);
        const float4 b0 = *reinterpret_cast<const float4*>(Bv + s * HID + cb * 8);
        const float4 b1 = *reinterpret_cast<const float4*>(Bv + s * HID + cb * 8 + 4);
        uint4 packed;
        packed.x = pack2bf(swishf(a0.x + b0.x), swishf(a0.y + b0.y));
        packed.y = pack2bf(swishf(a0.z + b0.z), swishf(a0.w + b0.w));
        packed.z = pack2bf(swishf(a1.x + b1.x), swishf(a1.y + b1.y));
        packed.w = pack2bf(swishf(a1.z + b1.z), swishf(a1.w + b1.w));
        int byte = e * 256 + ((cb * 16) ^ ((e & 7) << 4));
        *reinterpret_cast<uint4*>(reinterpret_cast<char*>(t_bf) + byte) = packed;
    }
    __syncthreads();

    // MFMA: out[128][128] = t @ W2 ; wave w owns edges w*32..w*32+31
    const int w = tid >> 6, l = tid & 63;
    const int lr = l & 15;    // A-row / B-col within fragment
    const int lk = l >> 4;    // k-group

    bf16x8 afr[2][4];
    #pragma unroll
    for (int rt = 0; rt < 2; ++rt) {
        #pragma unroll
        for (int ks = 0; ks < 4; ++ks) {
            int r = w * 32 + rt * 16 + lr;
            int byte = r * 256 + ((lk * 16 + ks * 64) ^ ((r & 7) << 4));
            afr[rt][ks] = *reinterpret_cast<const bf16x8*>(reinterpret_cast<const char*>(t_bf) + byte);
        }
    }

    f32x4 acc[2][8];
    #pragma unroll
    for (int rt = 0; rt < 2; ++rt)
        #pragma unroll
        for (int cf = 0; cf < 8; ++cf)
            acc[rt][cf] = (f32x4){0.0f, 0.0f, 0.0f, 0.0f};

    #pragma unroll
    for (int cf = 0; cf < 8; ++cf) {
        bf16x8 bfr[4];
        int n = cf * 16 + lr;
        #pragma unroll
        for (int ks = 0; ks < 4; ++ks) {
            int byte = n * 256 + ((lk * 16 + ks * 64) ^ ((n & 7) << 4));
            bfr[ks] = *reinterpret_cast<const bf16x8*>(reinterpret_cast<const char*>(w_bf) + byte);
        }
        #pragma unroll
        for (int rt = 0; rt < 2; ++rt)
            #pragma unroll
            for (int ks = 0; ks < 4; ++ks)
                acc[rt][cf] = __builtin_amdgcn_mfma_f32_16x16x32_bf16(afr[rt][ks], bfr[ks], acc[rt][cf], 0, 0, 0);
    }

    // epilogue: bias + swish + segmented accumulate (edges sorted by dst)
    #pragma unroll
    for (int rt = 0; rt < 2; ++rt) {
        int ebase = w * 32 + rt * 16 + lk * 4;   // lane holds 4 consecutive edges
        int d0 = s_dst[ebase], d1 = s_dst[ebase + 1], d2 = s_dst[ebase + 2], d3 = s_dst[ebase + 3];
        #pragma unroll
        for (int cf = 0; cf < 8; ++cf) {
            int col = cf * 16 + lr;
            float bias = b2[col];
            float v0 = swishf(acc[rt][cf][0] + bias);
            float v1 = swishf(acc[rt][cf][1] + bias);
            float v2 = swishf(acc[rt][cf][2] + bias);
            float v3 = swishf(acc[rt][cf][3] + bias);
            float run = v0;
            int dp = d0;
            if (d1 == dp) run += v1; else { atomicAdd(&agg[dp * HID + col], run); run = v1; dp = d1; }
            if (d2 == dp) run += v2; else { atomicAdd(&agg[dp * HID + col], run); run = v2; dp = d2; }
            if (d3 == dp) run += v3; else { atomicAdd(&agg[dp * HID + col], run); run = v3; dp = d3; }
            atomicAdd(&agg[dp * HID + col], run);
        }
    }
}

// ---------------------------------------------------------------- update MLP: [f, agg/deg, var_all] 258->128->128, +residual
__global__ __launch_bounds__(128) void update_kernel(
    const float* __restrict__ f, const float* __restrict__ agg,
    const int* __restrict__ cnt, const float* __restrict__ tpos,
    const float* __restrict__ vars,
    const float* __restrict__ U1, const float* __restrict__ b1,
    const float* __restrict__ U2, const float* __restrict__ b2,
    float* __restrict__ h)
{
    __shared__ float q[NB][HID + 4];
    const int o = threadIdx.x;
    const int n0 = blockIdx.x * NB;
    float acc[NB];
    float invd[NB];
    const float bias = b1[o];
    #pragma unroll
    for (int i = 0; i < NB; ++i) {
        acc[i] = bias;
        int c = cnt[n0 + i];
        invd[i] = 1.0f / (float)(c > 0 ? c : 1);
    }
    for (int kq = 0; kq < 32; ++kq) {
        float4 fv[NB];
        #pragma unroll
        for (int i = 0; i < NB; ++i)
            fv[i] = *reinterpret_cast<const float4*>(f + (n0 + i) * HID + kq * 4);
        #pragma unroll
        for (int kk = 0; kk < 4; ++kk) {
            float w = U1[(kq * 4 + kk) * HID + o];
            #pragma unroll
            for (int i = 0; i < NB; ++i)
                acc[i] += reinterpret_cast<const float*>(&fv[i])[kk] * w;
        }
    }
    for (int kq = 0; kq < 32; ++kq) {
        float4 av[NB];
        #pragma unroll
        for (int i = 0; i < NB; ++i) {
            av[i] = *reinterpret_cast<const float4*>(agg + (n0 + i) * HID + kq * 4);
            av[i].x *= invd[i]; av[i].y *= invd[i]; av[i].z *= invd[i]; av[i].w *= invd[i];
        }
        #pragma unroll
        for (int kk = 0; kk < 4; ++kk) {
            float w = U1[(HID + kq * 4 + kk) * HID + o];
            #pragma unroll
            for (int i = 0; i < NB; ++i)
                acc[i] += reinterpret_cast<const float*>(&av[i])[kk] * w;
        }
    }
    {
        float wt = U1[256 * HID + o], wv = U1[257 * HID + o];
        #pragma unroll
        for (int i = 0; i < NB; ++i) {
            int n = n0 + i;
            acc[i] += (tpos[n] * 0.25f) * wt + vars[n] * wv;
        }
    }
    #pragma unroll
    for (int i = 0; i < NB; ++i) q[i][o] = swishf(acc[i]);
    __syncthreads();
    float acc2[NB];
    const float bias2 = b2[o];
    #pragma unroll
    for (int i = 0; i < NB; ++i) acc2[i] = bias2;
    for (int kq = 0; kq < 32; ++kq) {
        #pragma unroll
        for (int kk = 0; kk < 4; ++kk) {
            float w = U2[(kq * 4 + kk) * HID + o];
            #pragma unroll
            for (int i = 0; i < NB; ++i) acc2[i] += q[i][kq * 4 + kk] * w;
        }
    }
    #pragma unroll
    for (int i = 0; i < NB; ++i)
        h[(n0 + i) * HID + o] = f[(n0 + i) * HID + o] + swishf(acc2[i]);
}

// ---------------------------------------------------------------- instance-norm stats (batch sorted)
__global__ __launch_bounds__(256) void stats_kernel(
    const float* __restrict__ h, const int* __restrict__ batch,
    float* __restrict__ dsum, float* __restrict__ dsq)
{
    const int feat = threadIdx.x & (HID - 1);
    const int sub = threadIdx.x >> 7;
    const int base = blockIdx.x * 64;
    float s = 0.0f, s2 = 0.0f;
    int cur = -1;
    for (int i = 0; i < 32; ++i) {
        int n = base + sub + 2 * i;
        int b = batch[n];
        float v = h[n * HID + feat];
        if (b != cur) {
            if (cur >= 0) {
                atomicAdd(&dsum[cur * HID + feat], s);
                atomicAdd(&dsq[cur * HID + feat], s2);
            }
            cur = b; s = 0.0f; s2 = 0.0f;
        }
        s += v; s2 += v * v;
    }
    if (cur >= 0) {
        atomicAdd(&dsum[cur * HID + feat], s);
        atomicAdd(&dsq[cur * HID + feat], s2);
    }
}

// ---------------------------------------------------------------- normalize
__global__ __launch_bounds__(256) void norm_kernel(
    const float* __restrict__ h, const int* __restrict__ batch,
    const float* __restrict__ dsum, const float* __restrict__ dsq,
    const float* __restrict__ gcount, float* __restrict__ f)
{
    const int gid = blockIdx.x * 256 + threadIdx.x;
    const int n = gid >> 7, feat = gid & (HID - 1);
    const int b = batch[n];
    const float gc = gcount[b];
    const float mean = dsum[b * HID + feat] / gc;
    const float var = dsq[b * HID + feat] / gc - mean * mean;
    f[gid] = (h[gid] - mean) * rsqrtf(var + EPSF);
}

// ---------------------------------------------------------------- conv head
__global__ __launch_bounds__(256) void head_kernel(
    const float* __restrict__ f, const float* __restrict__ u,
    const float* __restrict__ c1w, const float* __restrict__ c1b,
    const float* __restrict__ c2w, const float* __restrict__ c2b,
    float* __restrict__ out)
{
    __shared__ float fs[16][HID];
    __shared__ float y1[16][8][40];
    const int tid = threadIdx.x;
    const int n0 = blockIdx.x * 16;
    #pragma unroll
    for (int i = 0; i < 2; ++i) {
        int qi = tid + i * 256;
        int node = qi >> 5, kq = qi & 31;
        *reinterpret_cast<float4*>(&fs[node][kq * 4]) =
            *reinterpret_cast<const float4*>(f + (n0 + node) * HID + kq * 4);
    }
    __syncthreads();
    {
        const int node = tid >> 4;
        const int rem = tid & 15;
        const int o = rem >> 1;
        const int ph = rem & 1;
        const float cb = c1b[o];
        float wk[16];
        #pragma unroll
        for (int k = 0; k < 16; ++k) wk[k] = c1w[o * 16 + k];
        for (int p = ph * 19; p < ph * 19 + 19; ++p) {
            float acc = cb;
            #pragma unroll
            for (int k = 0; k < 16; ++k) acc += fs[node][p * 3 + k] * wk[k];
            y1[node][o][p] = swishf(acc);
        }
    }
    __syncthreads();
    const float cb2 = c2b[0];
    #pragma unroll
    for (int pass = 0; pass < 2; ++pass) {
        int unit = tid + pass * 256;
        if (unit < 16 * TW) {
            int node = unit / TW, t = unit % TW;
            float acc = cb2;
            #pragma unroll
            for (int o = 0; o < 8; ++o)
                #pragma unroll
                for (int k = 0; k < 14; ++k)
                    acc += y1[node][o][t + k] * c2w[o * 14 + k];
            int n = n0 + node;
            out[n * TW + t] = u[n * TW + (TW - 1)] + (0.016f * (float)(t + 1)) * acc;
        }
    }
}

// ---------------------------------------------------------------- launch
extern "C" void kernel_launch(void* const* d_in, const int* in_sizes, int n_in,
                              void* d_out, int out_size, void* d_ws, size_t ws_size,
                              hipStream_t stream)
{
    (void)in_sizes; (void)n_in; (void)out_size; (void)ws_size;
    const float* u      = (const float*)d_in[0];
    const float* xpos   = (const float*)d_in[1];
    const float* tpos   = (const float*)d_in[2];
    const float* vars   = (const float*)d_in[3];
    const int*   ei     = (const int*)d_in[4];
    const int*   batch  = (const int*)d_in[5];
    const float* emb_w1 = (const float*)d_in[6];
    const float* emb_b1 = (const float*)d_in[7];
    const float* emb_w2 = (const float*)d_in[8];
    const float* emb_b2 = (const float*)d_in[9];
    const float* m1_w   = (const float*)d_in[10];
    const float* m1_b   = (const float*)d_in[11];
    const float* m2_w   = (const float*)d_in[12];
    const float* m2_b   = (const float*)d_in[13];
    const float* u1_w   = (const float*)d_in[14];
    const float* u1_b   = (const float*)d_in[15];
    const float* u2_w   = (const float*)d_in[16];
    const float* u2_b   = (const float*)d_in[17];
    const float* c1w    = (const float*)d_in[18];
    const float* c1b    = (const float*)d_in[19];
    const float* c2w    = (const float*)d_in[20];
    const float* c2b    = (const float*)d_in[21];
    float* out = (float*)d_out;

    char* ws = (char*)d_ws;
    const size_t fbytes = (size_t)N_NODES * HID * sizeof(float);
    float* f      = (float*)(ws);
    float* Ah     = (float*)(ws + fbytes);          // A during message, h during update/norm
    float* Bv     = (float*)(ws + 2 * fbytes);
    float* agg    = (float*)(ws + 3 * fbytes);
    char*  p      = ws + 4 * fbytes;
    int* cnt      = (int*)p;               p += (size_t)N_NODES * 4;
    int* cursor   = (int*)p;               p += (size_t)N_NODES * 4;
    int* src_s    = (int*)p;               p += (size_t)N_EDGES * 4;
    int* dst_s    = (int*)p;               p += (size_t)N_EDGES * 4;
    int* bsum     = (int*)p;               p += 256 * 4;
    int* bpref    = (int*)p;               p += 256 * 4;
    float* dsum   = (float*)p;             p += BGRAPH * HID * 4;
    float* dsq    = (float*)p;             p += BGRAPH * HID * 4;
    float* gcount = (float*)p;             p += BGRAPH * 4;
    unsigned short* W2T = (unsigned short*)p;   // 6*128*128 bf16

    // CSR build (per call; edge_index is an input)
    hipMemsetAsync(cnt, 0, (size_t)N_NODES * 4, stream);
    count_kernel<<<N_EDGES / 256, 256, 0, stream>>>(ei, cnt);
    block_sum_kernel<<<N_NODES / 256, 256, 0, stream>>>(cnt, bsum);
    scan_bsum_kernel<<<1, 256, 0, stream>>>(bsum, bpref);
    offsets_kernel<<<N_NODES / 256, 256, 0, stream>>>(cnt, bpref, cursor);
    scatter_kernel<<<N_EDGES / 256, 256, 0, stream>>>(ei, cursor, src_s, dst_s);

    w2bf_kernel<<<LAYERS * HID * HID / 256, 256, 0, stream>>>(m2_w, W2T);
    gcount_kernel<<<1, 64, 0, stream>>>(batch, gcount);
    emb_kernel<<<N_NODES / NB, 128, 0, stream>>>(u, xpos, tpos, vars,
                                                 emb_w1, emb_b1, emb_w2, emb_b2, f);
    for (int l = 0; l < LAYERS; ++l) {
        abv_kernel<<<(N_NODES / NB) * HID / 256, 256, 0, stream>>>(
            f, u, xpos, tpos, vars,
            m1_w + (size_t)l * 284 * HID, m1_b + (size_t)l * HID, Ah, Bv);
        hipMemsetAsync(agg, 0, fbytes, stream);
        edge_mfma_kernel<<<N_EDGES / TILE_E, 256, 0, stream>>>(
            src_s, dst_s, Ah, Bv, W2T + (size_t)l * HID * HID,
            m2_b + (size_t)l * HID, agg);
        update_kernel<<<N_NODES / NB, 128, 0, stream>>>(
            f, agg, cnt, tpos, vars,
            u1_w + (size_t)l * 258 * HID, u1_b + (size_t)l * HID,
            u2_w + (size_t)l * HID * HID, u2_b + (size_t)l * HID, Ah);
        hipMemsetAsync(dsum, 0, (size_t)2 * BGRAPH * HID * 4, stream);
        stats_kernel<<<N_NODES / 64, 256, 0, stream>>>(Ah, batch, dsum, dsq);
        norm_kernel<<<(size_t)N_NODES * HID / 256, 256, 0, stream>>>(
            Ah, batch, dsum, dsq, gcount, f);
    }
    head_kernel<<<N_NODES / 16, 256, 0, stream>>>(f, u, c1w, c1b, c2w, c2b, out);
}

// Round 3
// 1773.704 us; speedup vs baseline: 3.7207x; 1.7865x over previous
//
#include <hip/hip_runtime.h>
#include <hip/hip_bf16.h>

#define N_NODES 65536
#define N_EDGES 393216
#define NB 8
#define HID 128
#define TW 25
#define LAYERS 6
#define BGRAPH 8
#define EPSF 1e-5f
#define TILE_E 128

typedef __attribute__((ext_vector_type(8))) short bf16x8;
typedef __attribute__((ext_vector_type(4))) float f32x4;

__device__ __forceinline__ float swishf(float x) {
    return x / (1.0f + __expf(-x));
}

__device__ __forceinline__ unsigned short f2bf(float x) {
    unsigned int u = __float_as_uint(x);
    u += 0x7fffu + ((u >> 16) & 1u);
    return (unsigned short)(u >> 16);
}

__device__ __forceinline__ unsigned int pack2bf(float lo, float hi) {
    return (unsigned int)f2bf(lo) | ((unsigned int)f2bf(hi) << 16);
}

// ---------------------------------------------------------------- gcount
__global__ void gcount_kernel(const int* __restrict__ batch, float* __restrict__ gcount) {
    int b = threadIdx.x;
    if (b >= BGRAPH) return;
    auto lb = [&](int key) {
        int lo = 0, hi = N_NODES;
        while (lo < hi) { int mid = (lo + hi) >> 1; if (batch[mid] < key) lo = mid + 1; else hi = mid; }
        return lo;
    };
    int c = lb(b + 1) - lb(b);
    gcount[b] = c > 0 ? (float)c : 1.0f;
}

// ---------------------------------------------------------------- CSR build
__global__ void count_kernel(const int* __restrict__ ei, int* __restrict__ cnt) {
    int e = blockIdx.x * 256 + threadIdx.x;
    if (e < N_EDGES) atomicAdd(&cnt[ei[N_EDGES + e]], 1);
}

__global__ __launch_bounds__(256) void block_sum_kernel(const int* __restrict__ cnt, int* __restrict__ bsum) {
    __shared__ int s[256];
    int t = threadIdx.x;
    s[t] = cnt[blockIdx.x * 256 + t];
    __syncthreads();
    for (int st = 128; st > 0; st >>= 1) {
        if (t < st) s[t] += s[t + st];
        __syncthreads();
    }
    if (t == 0) bsum[blockIdx.x] = s[0];
}

__global__ __launch_bounds__(256) void scan_bsum_kernel(const int* __restrict__ bsum, int* __restrict__ bpref) {
    __shared__ int s[256];
    int t = threadIdx.x;
    int orig = bsum[t];
    s[t] = orig;
    __syncthreads();
    for (int st = 1; st < 256; st <<= 1) {
        int v = (t >= st) ? s[t - st] : 0;
        __syncthreads();
        s[t] += v;
        __syncthreads();
    }
    bpref[t] = s[t] - orig;
}

__global__ __launch_bounds__(256) void offsets_kernel(const int* __restrict__ cnt, const int* __restrict__ bpref,
                                                      int* __restrict__ cursor) {
    __shared__ int s[256];
    int t = threadIdx.x;
    int base = blockIdx.x * 256;
    int orig = cnt[base + t];
    s[t] = orig;
    __syncthreads();
    for (int st = 1; st < 256; st <<= 1) {
        int v = (t >= st) ? s[t - st] : 0;
        __syncthreads();
        s[t] += v;
        __syncthreads();
    }
    cursor[base + t] = s[t] - orig + bpref[blockIdx.x];
}

__global__ void scatter_kernel(const int* __restrict__ ei, int* __restrict__ cursor,
                               int* __restrict__ src_s, int* __restrict__ dst_s) {
    int e = blockIdx.x * 256 + threadIdx.x;
    if (e >= N_EDGES) return;
    int d = ei[N_EDGES + e];
    int pos = atomicAdd(&cursor[d], 1);
    src_s[pos] = ei[e];
    dst_s[pos] = d;
}

// ---------------------------------------------------------------- weight prep (all bf16, transposed [o][k])
__global__ void w2bf_kernel(const float* __restrict__ m2_w, unsigned short* __restrict__ W2T) {
    int idx = blockIdx.x * 256 + threadIdx.x;   // 6*128*128
    int l = idx >> 14;
    int rem = idx & 16383;
    int n = rem >> 7, k = rem & 127;
    W2T[idx] = f2bf(m2_w[l * 16384 + k * HID + n]);
}

// wAB layout: [l][pass(A=0,B=1)][o=128][k=160]; k<128 = f-part, k>=128 = xin-part
__global__ void w1t_kernel(const float* __restrict__ m1_w, unsigned short* __restrict__ wAB) {
    int idx = blockIdx.x * 256 + threadIdx.x;   // 6*2*128*160 = 245760
    int l = idx / (2 * 128 * 160);
    int rem = idx % (2 * 128 * 160);
    int pass = rem / (128 * 160);
    int o = (rem % (128 * 160)) / 160;
    int k = rem % 160;
    const float* M = m1_w + (size_t)l * 284 * 128;
    float v;
    if (k < 128) {
        v = M[(pass ? 128 + k : k) * 128 + o];
    } else {
        int ku = k - 128;
        if (ku < 25) v = M[(256 + ku) * 128 + o];
        else if (ku == 25) v = M[281 * 128 + o];
        else if (ku == 26) v = M[282 * 128 + o];
        else if (ku == 27) v = M[283 * 128 + o];
        else v = 0.0f;
        if (pass) v = (ku <= 25) ? -v : 0.0f;
    }
    wAB[idx] = f2bf(v);
}

__global__ void u1t_kernel(const float* __restrict__ u1_w, unsigned short* __restrict__ U1T) {
    int idx = blockIdx.x * 256 + threadIdx.x;   // 6*128*256
    int l = idx >> 15;
    int o = (idx >> 8) & 127;
    int k = idx & 255;
    U1T[idx] = f2bf(u1_w[(size_t)l * 258 * 128 + k * 128 + o]);
}

__global__ void u2t_kernel(const float* __restrict__ u2_w, unsigned short* __restrict__ U2T) {
    int idx = blockIdx.x * 256 + threadIdx.x;   // 6*128*128
    int l = idx >> 14;
    int o = (idx >> 7) & 127;
    int k = idx & 127;
    U2T[idx] = f2bf(u2_w[(size_t)l * 16384 + k * 128 + o]);
}

// xin[n][32] = [u(25), pos/16, t/4, v, 0...] bf16
__global__ void xin_kernel(const float* __restrict__ u, const float* __restrict__ xpos,
                           const float* __restrict__ tpos, const float* __restrict__ vars,
                           unsigned short* __restrict__ xin) {
    int idx = blockIdx.x * 256 + threadIdx.x;   // 65536*32
    int n = idx >> 5, k = idx & 31;
    float v;
    if (k < 25) v = u[n * TW + k];
    else if (k == 25) v = xpos[n] * (1.0f / 16.0f);
    else if (k == 26) v = tpos[n] * 0.25f;
    else if (k == 27) v = vars[n];
    else v = 0.0f;
    xin[idx] = f2bf(v);
}

// ---------------------------------------------------------------- embedding MLP: 28 -> 128 -> 128
__global__ __launch_bounds__(128) void emb_kernel(
    const float* __restrict__ u, const float* __restrict__ xpos,
    const float* __restrict__ tpos, const float* __restrict__ vars,
    const float* __restrict__ w1, const float* __restrict__ b1,
    const float* __restrict__ w2, const float* __restrict__ b2,
    float* __restrict__ f, unsigned short* __restrict__ f_bf)
{
    __shared__ float q[NB][HID + 4];
    const int o = threadIdx.x;
    const int n0 = blockIdx.x * NB;
    float acc[NB];
    const float bias = b1[o];
    #pragma unroll
    for (int i = 0; i < NB; ++i) acc[i] = bias;
    for (int k = 0; k < TW; ++k) {
        float w = w1[k * HID + o];
        #pragma unroll
        for (int i = 0; i < NB; ++i) acc[i] += u[(n0 + i) * TW + k] * w;
    }
    {
        float wp = w1[25 * HID + o], wt = w1[26 * HID + o], wv = w1[27 * HID + o];
        #pragma unroll
        for (int i = 0; i < NB; ++i) {
            int n = n0 + i;
            acc[i] += (xpos[n] * (1.0f / 16.0f)) * wp + (tpos[n] * 0.25f) * wt + vars[n] * wv;
        }
    }
    #pragma unroll
    for (int i = 0; i < NB; ++i) q[i][o] = swishf(acc[i]);
    __syncthreads();
    float acc2[NB];
    const float bias2 = b2[o];
    #pragma unroll
    for (int i = 0; i < NB; ++i) acc2[i] = bias2;
    for (int k = 0; k < HID; ++k) {
        float w = w2[k * HID + o];
        #pragma unroll
        for (int i = 0; i < NB; ++i) acc2[i] += q[i][k] * w;
    }
    #pragma unroll
    for (int i = 0; i < NB; ++i) {
        float v = swishf(acc2[i]);
        f[(n0 + i) * HID + o] = v;
        f_bf[(n0 + i) * HID + o] = f2bf(v);
    }
}

// ---------------------------------------------------------------- abv via MFMA
// A  = [f_bf | xin] @ wA + b1 ; Bv = [f_bf | xin] @ wB   (K=160, per-wave 32 rows)
__global__ __launch_bounds__(256) void abv_mfma_kernel(
    const unsigned short* __restrict__ f_bf, const unsigned short* __restrict__ xin_bf,
    const unsigned short* __restrict__ wA, const unsigned short* __restrict__ wB,
    const float* __restrict__ b1,
    float* __restrict__ A, float* __restrict__ Bv)
{
    const int tid = threadIdx.x;
    const int w = tid >> 6, l = tid & 63;
    const int lr = l & 15, lk = l >> 4;
    const int nb = blockIdx.x * 128 + w * 32;

    bf16x8 afr[2][5];
    #pragma unroll
    for (int rt = 0; rt < 2; ++rt) {
        int row = nb + rt * 16 + lr;
        #pragma unroll
        for (int ks = 0; ks < 4; ++ks)
            afr[rt][ks] = *reinterpret_cast<const bf16x8*>(f_bf + row * HID + ks * 32 + lk * 8);
        afr[rt][4] = *reinterpret_cast<const bf16x8*>(xin_bf + row * 32 + lk * 8);
    }

    #pragma unroll
    for (int pass = 0; pass < 2; ++pass) {
        const unsigned short* Wp = pass ? wB : wA;
        f32x4 acc[2][8];
        #pragma unroll
        for (int rt = 0; rt < 2; ++rt)
            #pragma unroll
            for (int cf = 0; cf < 8; ++cf)
                acc[rt][cf] = (f32x4){0.0f, 0.0f, 0.0f, 0.0f};
        #pragma unroll
        for (int cf = 0; cf < 8; ++cf) {
            const unsigned short* wrow = Wp + (cf * 16 + lr) * 160 + lk * 8;
            #pragma unroll
            for (int ks = 0; ks < 5; ++ks) {
                bf16x8 bfr = *reinterpret_cast<const bf16x8*>(wrow + ks * 32);
                acc[0][cf] = __builtin_amdgcn_mfma_f32_16x16x32_bf16(afr[0][ks], bfr, acc[0][cf], 0, 0, 0);
                acc[1][cf] = __builtin_amdgcn_mfma_f32_16x16x32_bf16(afr[1][ks], bfr, acc[1][cf], 0, 0, 0);
            }
        }
        float* Op = pass ? Bv : A;
        #pragma unroll
        for (int cf = 0; cf < 8; ++cf) {
            int col = cf * 16 + lr;
            float bb = pass ? 0.0f : b1[col];
            #pragma unroll
            for (int rt = 0; rt < 2; ++rt) {
                #pragma unroll
                for (int j = 0; j < 4; ++j) {
                    int row = nb + rt * 16 + lk * 4 + j;
                    Op[row * HID + col] = acc[rt][cf][j] + bb;
                }
            }
        }
    }
}

// ---------------------------------------------------------------- fused edge kernel (CSR-sorted, MFMA, barrier-free)
__global__ __launch_bounds__(256) void edge_mfma_kernel(
    const int* __restrict__ src_s, const int* __restrict__ dst_s,
    const float* __restrict__ A, const float* __restrict__ Bv,
    const unsigned short* __restrict__ W2T, const float* __restrict__ b2,
    float* __restrict__ agg)
{
    __shared__ unsigned short t_bf[TILE_E * HID];   // 32 KB, XOR-swizzled rows
    const int tid = threadIdx.x;
    const int w = tid >> 6, l = tid & 63;
    const int lr = l & 15, lk = l >> 4;
    const int e0 = blockIdx.x * TILE_E;

    // gather + swish -> bf16 LDS: wave handles its own 32 edges (rows w*32..w*32+31)
    #pragma unroll
    for (int i = 0; i < 8; ++i) {
        int un = l + i * 64;
        int e = w * 32 + (un >> 4), cb = un & 15;
        int d = dst_s[e0 + e], s = src_s[e0 + e];
        const float4 a0 = *reinterpret_cast<const float4*>(A + d * HID + cb * 8);
        const float4 a1 = *reinterpret_cast<const float4*>(A + d * HID + cb * 8 + 4);
        const float4 b0 = *reinterpret_cast<const float4*>(Bv + s * HID + cb * 8);
        const float4 b1 = *reinterpret_cast<const float4*>(Bv + s * HID + cb * 8 + 4);
        uint4 packed;
        packed.x = pack2bf(swishf(a0.x + b0.x), swishf(a0.y + b0.y));
        packed.y = pack2bf(swishf(a0.z + b0.z), swishf(a0.w + b0.w));
        packed.z = pack2bf(swishf(a1.x + b1.x), swishf(a1.y + b1.y));
        packed.w = pack2bf(swishf(a1.z + b1.z), swishf(a1.w + b1.w));
        int byte = e * 256 + ((cb * 16) ^ ((e & 7) << 4));
        *reinterpret_cast<uint4*>(reinterpret_cast<char*>(t_bf) + byte) = packed;
    }
    // no barrier: each wave reads only the rows it wrote (compiler orders via lgkmcnt)

    bf16x8 afr[2][4];
    #pragma unroll
    for (int rt = 0; rt < 2; ++rt) {
        #pragma unroll
        for (int ks = 0; ks < 4; ++ks) {
            int r = w * 32 + rt * 16 + lr;
            int byte = r * 256 + ((lk * 16 + ks * 64) ^ ((r & 7) << 4));
            afr[rt][ks] = *reinterpret_cast<const bf16x8*>(reinterpret_cast<const char*>(t_bf) + byte);
        }
    }

    f32x4 acc[2][8];
    #pragma unroll
    for (int rt = 0; rt < 2; ++rt)
        #pragma unroll
        for (int cf = 0; cf < 8; ++cf)
            acc[rt][cf] = (f32x4){0.0f, 0.0f, 0.0f, 0.0f};

    #pragma unroll
    for (int cf = 0; cf < 8; ++cf) {
        const unsigned short* wrow = W2T + (cf * 16 + lr) * HID + lk * 8;
        #pragma unroll
        for (int ks = 0; ks < 4; ++ks) {
            bf16x8 bfr = *reinterpret_cast<const bf16x8*>(wrow + ks * 32);
            acc[0][cf] = __builtin_amdgcn_mfma_f32_16x16x32_bf16(afr[0][ks], bfr, acc[0][cf], 0, 0, 0);
            acc[1][cf] = __builtin_amdgcn_mfma_f32_16x16x32_bf16(afr[1][ks], bfr, acc[1][cf], 0, 0, 0);
        }
    }

    // epilogue: bias + swish + segmented accumulate (edges sorted by dst)
    #pragma unroll
    for (int rt = 0; rt < 2; ++rt) {
        int ebase = e0 + w * 32 + rt * 16 + lk * 4;
        int d0 = dst_s[ebase], d1 = dst_s[ebase + 1], d2 = dst_s[ebase + 2], d3 = dst_s[ebase + 3];
        #pragma unroll
        for (int cf = 0; cf < 8; ++cf) {
            int col = cf * 16 + lr;
            float bias = b2[col];
            float v0 = swishf(acc[rt][cf][0] + bias);
            float v1 = swishf(acc[rt][cf][1] + bias);
            float v2 = swishf(acc[rt][cf][2] + bias);
            float v3 = swishf(acc[rt][cf][3] + bias);
            float run = v0;
            int dp = d0;
            if (d1 == dp) run += v1; else { atomicAdd(&agg[dp * HID + col], run); run = v1; dp = d1; }
            if (d2 == dp) run += v2; else { atomicAdd(&agg[dp * HID + col], run); run = v2; dp = d2; }
            if (d3 == dp) run += v3; else { atomicAdd(&agg[dp * HID + col], run); run = v3; dp = d3; }
            atomicAdd(&agg[dp * HID + col], run);
        }
    }
}

// ---------------------------------------------------------------- update via MFMA
// q = swish([f_bf | agg*invd] @ U1 + tv + b1);  h = f + swish(q @ U2 + b2)
__global__ __launch_bounds__(256) void update_mfma_kernel(
    const unsigned short* __restrict__ f_bf, const float* __restrict__ agg,
    const int* __restrict__ cnt, const float* __restrict__ f32f,
    const float* __restrict__ tpos, const float* __restrict__ vars,
    const unsigned short* __restrict__ U1T, const float* __restrict__ u1tv,
    const float* __restrict__ b1, const unsigned short* __restrict__ U2T,
    const float* __restrict__ b2, float* __restrict__ h)
{
    __shared__ unsigned short q_lds[4 * 32 * HID];   // 32 KB, per-wave 8 KB regions
    const int tid = threadIdx.x;
    const int w = tid >> 6, l = tid & 63;
    const int lr = l & 15, lk = l >> 4;
    const int nb = blockIdx.x * 128 + w * 32;
    char* qbase = reinterpret_cast<char*>(q_lds) + w * 8192;

    float invd[2];
    #pragma unroll
    for (int rt = 0; rt < 2; ++rt) {
        int c = cnt[nb + rt * 16 + lr];
        invd[rt] = 1.0f / (float)(c > 0 ? c : 1);
    }

    f32x4 acc[2][8];
    #pragma unroll
    for (int rt = 0; rt < 2; ++rt)
        #pragma unroll
        for (int cf = 0; cf < 8; ++cf)
            acc[rt][cf] = (f32x4){0.0f, 0.0f, 0.0f, 0.0f};

    #pragma unroll
    for (int ks = 0; ks < 8; ++ks) {
        bf16x8 afr[2];
        #pragma unroll
        for (int rt = 0; rt < 2; ++rt) {
            int row = nb + rt * 16 + lr;
            if (ks < 4) {
                afr[rt] = *reinterpret_cast<const bf16x8*>(f_bf + row * HID + ks * 32 + lk * 8);
            } else {
                const float* ap = agg + row * HID + (ks - 4) * 32 + lk * 8;
                float4 a0 = *reinterpret_cast<const float4*>(ap);
                float4 a1 = *reinterpret_cast<const float4*>(ap + 4);
                float iv = invd[rt];
                union { bf16x8 v; unsigned int u[4]; } t;
                t.u[0] = pack2bf(a0.x * iv, a0.y * iv);
                t.u[1] = pack2bf(a0.z * iv, a0.w * iv);
                t.u[2] = pack2bf(a1.x * iv, a1.y * iv);
                t.u[3] = pack2bf(a1.z * iv, a1.w * iv);
                afr[rt] = t.v;
            }
        }
        #pragma unroll
        for (int cf = 0; cf < 8; ++cf) {
            bf16x8 bfr = *reinterpret_cast<const bf16x8*>(U1T + (cf * 16 + lr) * 256 + ks * 32 + lk * 8);
            acc[0][cf] = __builtin_amdgcn_mfma_f32_16x16x32_bf16(afr[0], bfr, acc[0][cf], 0, 0, 0);
            acc[1][cf] = __builtin_amdgcn_mfma_f32_16x16x32_bf16(afr[1], bfr, acc[1][cf], 0, 0, 0);
        }
    }

    // epilogue 1: add tv + bias, swish, write q to own LDS region (swizzled bf16)
    float tn[2][4], vn[2][4];
    #pragma unroll
    for (int rt = 0; rt < 2; ++rt)
        #pragma unroll
        for (int j = 0; j < 4; ++j) {
            int row = nb + rt * 16 + lk * 4 + j;
            tn[rt][j] = tpos[row] * 0.25f;
            vn[rt][j] = vars[row];
        }
    #pragma unroll
    for (int cf = 0; cf < 8; ++cf) {
        int col = cf * 16 + lr;
        float bb = b1[col], wt = u1tv[col], wv = u1tv[HID + col];
        #pragma unroll
        for (int rt = 0; rt < 2; ++rt)
            #pragma unroll
            for (int j = 0; j < 4; ++j) {
                float qv = swishf(acc[rt][cf][j] + bb + tn[rt][j] * wt + vn[rt][j] * wv);
                int rloc = rt * 16 + lk * 4 + j;
                *reinterpret_cast<unsigned short*>(qbase + rloc * 256 + ((col * 2) ^ ((rloc & 7) << 4))) = f2bf(qv);
            }
    }
    // no barrier: wave reads only its own region

    f32x4 acc2[2][8];
    #pragma unroll
    for (int rt = 0; rt < 2; ++rt)
        #pragma unroll
        for (int cf = 0; cf < 8; ++cf)
            acc2[rt][cf] = (f32x4){0.0f, 0.0f, 0.0f, 0.0f};

    #pragma unroll
    for (int ks = 0; ks < 4; ++ks) {
        bf16x8 afr[2];
        #pragma unroll
        for (int rt = 0; rt < 2; ++rt) {
            int rloc = rt * 16 + lr;
            afr[rt] = *reinterpret_cast<const bf16x8*>(qbase + rloc * 256 + ((ks * 64 + lk * 16) ^ ((rloc & 7) << 4)));
        }
        #pragma unroll
        for (int cf = 0; cf < 8; ++cf) {
            bf16x8 bfr = *reinterpret_cast<const bf16x8*>(U2T + (cf * 16 + lr) * HID + ks * 32 + lk * 8);
            acc2[0][cf] = __builtin_amdgcn_mfma_f32_16x16x32_bf16(afr[0], bfr, acc2[0][cf], 0, 0, 0);
            acc2[1][cf] = __builtin_amdgcn_mfma_f32_16x16x32_bf16(afr[1], bfr, acc2[1][cf], 0, 0, 0);
        }
    }

    // epilogue 2: h = f + swish(acc2 + b2)
    #pragma unroll
    for (int cf = 0; cf < 8; ++cf) {
        int col = cf * 16 + lr;
        float bb = b2[col];
        #pragma unroll
        for (int rt = 0; rt < 2; ++rt)
            #pragma unroll
            for (int j = 0; j < 4; ++j) {
                int row = nb + rt * 16 + lk * 4 + j;
                h[row * HID + col] = f32f[row * HID + col] + swishf(acc2[rt][cf][j] + bb);
            }
    }
}

// ---------------------------------------------------------------- instance-norm stats (batch sorted)
__global__ __launch_bounds__(256) void stats_kernel(
    const float* __restrict__ h, const int* __restrict__ batch,
    float* __restrict__ dsum, float* __restrict__ dsq)
{
    const int feat = threadIdx.x & (HID - 1);
    const int sub = threadIdx.x >> 7;
    const int base = blockIdx.x * 64;
    float s = 0.0f, s2 = 0.0f;
    int cur = -1;
    for (int i = 0; i < 32; ++i) {
        int n = base + sub + 2 * i;
        int b = batch[n];
        float v = h[n * HID + feat];
        if (b != cur) {
            if (cur >= 0) {
                atomicAdd(&dsum[cur * HID + feat], s);
                atomicAdd(&dsq[cur * HID + feat], s2);
            }
            cur = b; s = 0.0f; s2 = 0.0f;
        }
        s += v; s2 += v * v;
    }
    if (cur >= 0) {
        atomicAdd(&dsum[cur * HID + feat], s);
        atomicAdd(&dsq[cur * HID + feat], s2);
    }
}

// ---------------------------------------------------------------- normalize (writes f32 + bf16)
__global__ __launch_bounds__(256) void norm_kernel(
    const float* __restrict__ h, const int* __restrict__ batch,
    const float* __restrict__ dsum, const float* __restrict__ dsq,
    const float* __restrict__ gcount, float* __restrict__ f,
    unsigned short* __restrict__ f_bf)
{
    const int gid = blockIdx.x * 256 + threadIdx.x;   // N*16
    const int n = gid >> 4, c0 = (gid & 15) * 8;
    const int b = batch[n];
    const float inv = 1.0f / gcount[b];
    float4 h0 = *reinterpret_cast<const float4*>(h + n * HID + c0);
    float4 h1 = *reinterpret_cast<const float4*>(h + n * HID + c0 + 4);
    float o[8];
    const float* hv = reinterpret_cast<const float*>(&h0);
    #pragma unroll
    for (int i = 0; i < 8; ++i) {
        float hx = (i < 4) ? reinterpret_cast<const float*>(&h0)[i] : reinterpret_cast<const float*>(&h1)[i - 4];
        float mean = dsum[b * HID + c0 + i] * inv;
        float var = dsq[b * HID + c0 + i] * inv - mean * mean;
        o[i] = (hx - mean) * rsqrtf(var + EPSF);
    }
    (void)hv;
    float4 o0 = {o[0], o[1], o[2], o[3]};
    float4 o1 = {o[4], o[5], o[6], o[7]};
    *reinterpret_cast<float4*>(f + n * HID + c0) = o0;
    *reinterpret_cast<float4*>(f + n * HID + c0 + 4) = o1;
    uint4 pb;
    pb.x = pack2bf(o[0], o[1]);
    pb.y = pack2bf(o[2], o[3]);
    pb.z = pack2bf(o[4], o[5]);
    pb.w = pack2bf(o[6], o[7]);
    *reinterpret_cast<uint4*>(f_bf + n * HID + c0) = pb;
}

// ---------------------------------------------------------------- conv head
__global__ __launch_bounds__(256) void head_kernel(
    const float* __restrict__ f, const float* __restrict__ u,
    const float* __restrict__ c1w, const float* __restrict__ c1b,
    const float* __restrict__ c2w, const float* __restrict__ c2b,
    float* __restrict__ out)
{
    __shared__ float fs[16][HID];
    __shared__ float y1[16][8][40];
    const int tid = threadIdx.x;
    const int n0 = blockIdx.x * 16;
    #pragma unroll
    for (int i = 0; i < 2; ++i) {
        int qi = tid + i * 256;
        int node = qi >> 5, kq = qi & 31;
        *reinterpret_cast<float4*>(&fs[node][kq * 4]) =
            *reinterpret_cast<const float4*>(f + (n0 + node) * HID + kq * 4);
    }
    __syncthreads();
    {
        const int node = tid >> 4;
        const int rem = tid & 15;
        const int o = rem >> 1;
        const int ph = rem & 1;
        const float cb = c1b[o];
        float wk[16];
        #pragma unroll
        for (int k = 0; k < 16; ++k) wk[k] = c1w[o * 16 + k];
        for (int p = ph * 19; p < ph * 19 + 19; ++p) {
            float acc = cb;
            #pragma unroll
            for (int k = 0; k < 16; ++k) acc += fs[node][p * 3 + k] * wk[k];
            y1[node][o][p] = swishf(acc);
        }
    }
    __syncthreads();
    const float cb2 = c2b[0];
    #pragma unroll
    for (int pass = 0; pass < 2; ++pass) {
        int unit = tid + pass * 256;
        if (unit < 16 * TW) {
            int node = unit / TW, t = unit % TW;
            float acc = cb2;
            #pragma unroll
            for (int o = 0; o < 8; ++o)
                #pragma unroll
                for (int k = 0; k < 14; ++k)
                    acc += y1[node][o][t + k] * c2w[o * 14 + k];
            int n = n0 + node;
            out[n * TW + t] = u[n * TW + (TW - 1)] + (0.016f * (float)(t + 1)) * acc;
        }
    }
}

// ---------------------------------------------------------------- launch
extern "C" void kernel_launch(void* const* d_in, const int* in_sizes, int n_in,
                              void* d_out, int out_size, void* d_ws, size_t ws_size,
                              hipStream_t stream)
{
    (void)in_sizes; (void)n_in; (void)out_size; (void)ws_size;
    const float* u      = (const float*)d_in[0];
    const float* xpos   = (const float*)d_in[1];
    const float* tpos   = (const float*)d_in[2];
    const float* vars   = (const float*)d_in[3];
    const int*   ei     = (const int*)d_in[4];
    const int*   batch  = (const int*)d_in[5];
    const float* emb_w1 = (const float*)d_in[6];
    const float* emb_b1 = (const float*)d_in[7];
    const float* emb_w2 = (const float*)d_in[8];
    const float* emb_b2 = (const float*)d_in[9];
    const float* m1_w   = (const float*)d_in[10];
    const float* m1_b   = (const float*)d_in[11];
    const float* m2_w   = (const float*)d_in[12];
    const float* m2_b   = (const float*)d_in[13];
    const float* u1_w   = (const float*)d_in[14];
    const float* u1_b   = (const float*)d_in[15];
    const float* u2_w   = (const float*)d_in[16];
    const float* u2_b   = (const float*)d_in[17];
    const float* c1w    = (const float*)d_in[18];
    const float* c1b    = (const float*)d_in[19];
    const float* c2w    = (const float*)d_in[20];
    const float* c2b    = (const float*)d_in[21];
    float* out = (float*)d_out;

    char* ws = (char*)d_ws;
    const size_t fbytes = (size_t)N_NODES * HID * sizeof(float);
    float* f      = (float*)(ws);
    float* Ah     = (float*)(ws + fbytes);          // A during message, h during update/norm
    float* Bv     = (float*)(ws + 2 * fbytes);
    float* agg    = (float*)(ws + 3 * fbytes);
    char*  p      = ws + 4 * fbytes;
    unsigned short* f_bf   = (unsigned short*)p;  p += (size_t)N_NODES * HID * 2;
    unsigned short* xin_bf = (unsigned short*)p;  p += (size_t)N_NODES * 32 * 2;
    int* cnt      = (int*)p;               p += (size_t)N_NODES * 4;
    int* cursor   = (int*)p;               p += (size_t)N_NODES * 4;
    int* src_s    = (int*)p;               p += (size_t)N_EDGES * 4;
    int* dst_s    = (int*)p;               p += (size_t)N_EDGES * 4;
    int* bsum     = (int*)p;               p += 256 * 4;
    int* bpref    = (int*)p;               p += 256 * 4;
    float* dsum   = (float*)p;             p += BGRAPH * HID * 4;
    float* dsq    = (float*)p;             p += BGRAPH * HID * 4;
    float* gcount = (float*)p;             p += BGRAPH * 4;
    unsigned short* W2T = (unsigned short*)p;  p += (size_t)LAYERS * HID * HID * 2;
    unsigned short* wAB = (unsigned short*)p;  p += (size_t)LAYERS * 2 * 128 * 160 * 2;
    unsigned short* U1T = (unsigned short*)p;  p += (size_t)LAYERS * 128 * 256 * 2;
    unsigned short* U2T = (unsigned short*)p;  p += (size_t)LAYERS * 128 * 128 * 2;

    // CSR build
    hipMemsetAsync(cnt, 0, (size_t)N_NODES * 4, stream);
    count_kernel<<<N_EDGES / 256, 256, 0, stream>>>(ei, cnt);
    block_sum_kernel<<<N_NODES / 256, 256, 0, stream>>>(cnt, bsum);
    scan_bsum_kernel<<<1, 256, 0, stream>>>(bsum, bpref);
    offsets_kernel<<<N_NODES / 256, 256, 0, stream>>>(cnt, bpref, cursor);
    scatter_kernel<<<N_EDGES / 256, 256, 0, stream>>>(ei, cursor, src_s, dst_s);

    // weight / input prep
    w2bf_kernel<<<LAYERS * HID * HID / 256, 256, 0, stream>>>(m2_w, W2T);
    w1t_kernel<<<LAYERS * 2 * 128 * 160 / 256, 256, 0, stream>>>(m1_w, wAB);
    u1t_kernel<<<LAYERS * 128 * 256 / 256, 256, 0, stream>>>(u1_w, U1T);
    u2t_kernel<<<LAYERS * 128 * 128 / 256, 256, 0, stream>>>(u2_w, U2T);
    xin_kernel<<<N_NODES * 32 / 256, 256, 0, stream>>>(u, xpos, tpos, vars, xin_bf);
    gcount_kernel<<<1, 64, 0, stream>>>(batch, gcount);
    emb_kernel<<<N_NODES / NB, 128, 0, stream>>>(u, xpos, tpos, vars,
                                                 emb_w1, emb_b1, emb_w2, emb_b2, f, f_bf);

    for (int l = 0; l < LAYERS; ++l) {
        abv_mfma_kernel<<<N_NODES / 128, 256, 0, stream>>>(
            f_bf, xin_bf,
            wAB + (size_t)l * 2 * 128 * 160,
            wAB + (size_t)l * 2 * 128 * 160 + 128 * 160,
            m1_b + (size_t)l * HID, Ah, Bv);
        hipMemsetAsync(agg, 0, fbytes, stream);
        edge_mfma_kernel<<<N_EDGES / TILE_E, 256, 0, stream>>>(
            src_s, dst_s, Ah, Bv, W2T + (size_t)l * HID * HID,
            m2_b + (size_t)l * HID, agg);
        update_mfma_kernel<<<N_NODES / 128, 256, 0, stream>>>(
            f_bf, agg, cnt, f, tpos, vars,
            U1T + (size_t)l * 128 * 256,
            u1_w + (size_t)l * 258 * 128 + 256 * 128,
            u1_b + (size_t)l * HID,
            U2T + (size_t)l * 128 * 128,
            u2_b + (size_t)l * HID, Ah);
        hipMemsetAsync(dsum, 0, (size_t)2 * BGRAPH * HID * 4, stream);
        stats_kernel<<<N_NODES / 64, 256, 0, stream>>>(Ah, batch, dsum, dsq);
        norm_kernel<<<N_NODES * 16 / 256, 256, 0, stream>>>(
            Ah, batch, dsum, dsq, gcount, f, f_bf);
    }
    head_kernel<<<N_NODES / 16, 256, 0, stream>>>(f, u, c1w, c1b, c2w, c2b, out);
}

// Round 4
// 1553.097 us; speedup vs baseline: 4.2492x; 1.1420x over previous
//
#include <hip/hip_runtime.h>
#include <hip/hip_bf16.h>

#define N_NODES 65536
#define N_EDGES 393216
#define NB 8
#define HID 128
#define TW 25
#define LAYERS 6
#define BGRAPH 8
#define EPSF 1e-5f
#define TILE_E 128

typedef __attribute__((ext_vector_type(8))) short bf16x8;
typedef __attribute__((ext_vector_type(4))) float f32x4;

__device__ __forceinline__ float swishf(float x) {
    return x / (1.0f + __expf(-x));
}

__device__ __forceinline__ unsigned short f2bf(float x) {
    unsigned int u = __float_as_uint(x);
    u += 0x7fffu + ((u >> 16) & 1u);
    return (unsigned short)(u >> 16);
}

__device__ __forceinline__ unsigned int pack2bf(float lo, float hi) {
    return (unsigned int)f2bf(lo) | ((unsigned int)f2bf(hi) << 16);
}

// ---------------------------------------------------------------- gcount
__global__ void gcount_kernel(const int* __restrict__ batch, float* __restrict__ gcount) {
    int b = threadIdx.x;
    if (b >= BGRAPH) return;
    auto lb = [&](int key) {
        int lo = 0, hi = N_NODES;
        while (lo < hi) { int mid = (lo + hi) >> 1; if (batch[mid] < key) lo = mid + 1; else hi = mid; }
        return lo;
    };
    int c = lb(b + 1) - lb(b);
    gcount[b] = c > 0 ? (float)c : 1.0f;
}

// ---------------------------------------------------------------- CSR build
__global__ void count_kernel(const int* __restrict__ ei, int* __restrict__ cnt) {
    int e = blockIdx.x * 256 + threadIdx.x;
    if (e < N_EDGES) atomicAdd(&cnt[ei[N_EDGES + e]], 1);
}

__global__ __launch_bounds__(256) void block_sum_kernel(const int* __restrict__ cnt, int* __restrict__ bsum) {
    __shared__ int s[256];
    int t = threadIdx.x;
    s[t] = cnt[blockIdx.x * 256 + t];
    __syncthreads();
    for (int st = 128; st > 0; st >>= 1) {
        if (t < st) s[t] += s[t + st];
        __syncthreads();
    }
    if (t == 0) bsum[blockIdx.x] = s[0];
}

__global__ __launch_bounds__(256) void scan_bsum_kernel(const int* __restrict__ bsum, int* __restrict__ bpref) {
    __shared__ int s[256];
    int t = threadIdx.x;
    int orig = bsum[t];
    s[t] = orig;
    __syncthreads();
    for (int st = 1; st < 256; st <<= 1) {
        int v = (t >= st) ? s[t - st] : 0;
        __syncthreads();
        s[t] += v;
        __syncthreads();
    }
    bpref[t] = s[t] - orig;
}

__global__ __launch_bounds__(256) void offsets_kernel(const int* __restrict__ cnt, const int* __restrict__ bpref,
                                                      int* __restrict__ cursor) {
    __shared__ int s[256];
    int t = threadIdx.x;
    int base = blockIdx.x * 256;
    int orig = cnt[base + t];
    s[t] = orig;
    __syncthreads();
    for (int st = 1; st < 256; st <<= 1) {
        int v = (t >= st) ? s[t - st] : 0;
        __syncthreads();
        s[t] += v;
        __syncthreads();
    }
    cursor[base + t] = s[t] - orig + bpref[blockIdx.x];
}

__global__ void scatter_kernel(const int* __restrict__ ei, int* __restrict__ cursor,
                               int* __restrict__ src_s, int* __restrict__ dst_s) {
    int e = blockIdx.x * 256 + threadIdx.x;
    if (e >= N_EDGES) return;
    int d = ei[N_EDGES + e];
    int pos = atomicAdd(&cursor[d], 1);
    src_s[pos] = ei[e];
    dst_s[pos] = d;
}

// ---------------------------------------------------------------- weight prep (all bf16, transposed [o][k])
__global__ void w2bf_kernel(const float* __restrict__ m2_w, unsigned short* __restrict__ W2T) {
    int idx = blockIdx.x * 256 + threadIdx.x;   // 6*128*128
    int l = idx >> 14;
    int rem = idx & 16383;
    int n = rem >> 7, k = rem & 127;
    W2T[idx] = f2bf(m2_w[l * 16384 + k * HID + n]);
}

// wAB layout: [l][pass(A=0,B=1)][o=128][k=160]; k<128 = f-part, k>=128 = xin-part
__global__ void w1t_kernel(const float* __restrict__ m1_w, unsigned short* __restrict__ wAB) {
    int idx = blockIdx.x * 256 + threadIdx.x;   // 6*2*128*160 = 245760
    int l = idx / (2 * 128 * 160);
    int rem = idx % (2 * 128 * 160);
    int pass = rem / (128 * 160);
    int o = (rem % (128 * 160)) / 160;
    int k = rem % 160;
    const float* M = m1_w + (size_t)l * 284 * 128;
    float v;
    if (k < 128) {
        v = M[(pass ? 128 + k : k) * 128 + o];
    } else {
        int ku = k - 128;
        if (ku < 25) v = M[(256 + ku) * 128 + o];
        else if (ku == 25) v = M[281 * 128 + o];
        else if (ku == 26) v = M[282 * 128 + o];
        else if (ku == 27) v = M[283 * 128 + o];
        else v = 0.0f;
        if (pass) v = (ku <= 25) ? -v : 0.0f;
    }
    wAB[idx] = f2bf(v);
}

__global__ void u1t_kernel(const float* __restrict__ u1_w, unsigned short* __restrict__ U1T) {
    int idx = blockIdx.x * 256 + threadIdx.x;   // 6*128*256
    int l = idx >> 15;
    int o = (idx >> 8) & 127;
    int k = idx & 255;
    U1T[idx] = f2bf(u1_w[(size_t)l * 258 * 128 + k * 128 + o]);
}

__global__ void u2t_kernel(const float* __restrict__ u2_w, unsigned short* __restrict__ U2T) {
    int idx = blockIdx.x * 256 + threadIdx.x;   // 6*128*128
    int l = idx >> 14;
    int o = (idx >> 7) & 127;
    int k = idx & 127;
    U2T[idx] = f2bf(u2_w[(size_t)l * 16384 + k * 128 + o]);
}

// xin[n][32] = [u(25), pos/16, t/4, v, 0...] bf16
__global__ void xin_kernel(const float* __restrict__ u, const float* __restrict__ xpos,
                           const float* __restrict__ tpos, const float* __restrict__ vars,
                           unsigned short* __restrict__ xin) {
    int idx = blockIdx.x * 256 + threadIdx.x;   // 65536*32
    int n = idx >> 5, k = idx & 31;
    float v;
    if (k < 25) v = u[n * TW + k];
    else if (k == 25) v = xpos[n] * (1.0f / 16.0f);
    else if (k == 26) v = tpos[n] * 0.25f;
    else if (k == 27) v = vars[n];
    else v = 0.0f;
    xin[idx] = f2bf(v);
}

// ---------------------------------------------------------------- embedding MLP: 28 -> 128 -> 128
__global__ __launch_bounds__(128) void emb_kernel(
    const float* __restrict__ u, const float* __restrict__ xpos,
    const float* __restrict__ tpos, const float* __restrict__ vars,
    const float* __restrict__ w1, const float* __restrict__ b1,
    const float* __restrict__ w2, const float* __restrict__ b2,
    float* __restrict__ f, unsigned short* __restrict__ f_bf)
{
    __shared__ float q[NB][HID + 4];
    const int o = threadIdx.x;
    const int n0 = blockIdx.x * NB;
    float acc[NB];
    const float bias = b1[o];
    #pragma unroll
    for (int i = 0; i < NB; ++i) acc[i] = bias;
    for (int k = 0; k < TW; ++k) {
        float w = w1[k * HID + o];
        #pragma unroll
        for (int i = 0; i < NB; ++i) acc[i] += u[(n0 + i) * TW + k] * w;
    }
    {
        float wp = w1[25 * HID + o], wt = w1[26 * HID + o], wv = w1[27 * HID + o];
        #pragma unroll
        for (int i = 0; i < NB; ++i) {
            int n = n0 + i;
            acc[i] += (xpos[n] * (1.0f / 16.0f)) * wp + (tpos[n] * 0.25f) * wt + vars[n] * wv;
        }
    }
    #pragma unroll
    for (int i = 0; i < NB; ++i) q[i][o] = swishf(acc[i]);
    __syncthreads();
    float acc2[NB];
    const float bias2 = b2[o];
    #pragma unroll
    for (int i = 0; i < NB; ++i) acc2[i] = bias2;
    for (int k = 0; k < HID; ++k) {
        float w = w2[k * HID + o];
        #pragma unroll
        for (int i = 0; i < NB; ++i) acc2[i] += q[i][k] * w;
    }
    #pragma unroll
    for (int i = 0; i < NB; ++i) {
        float v = swishf(acc2[i]);
        f[(n0 + i) * HID + o] = v;
        f_bf[(n0 + i) * HID + o] = f2bf(v);
    }
}

// ---------------------------------------------------------------- abv via MFMA -> bf16 outputs
// A  = [f_bf | xin] @ wA + b1 ; Bv = [f_bf | xin] @ wB   (K=160, per-wave 32 rows)
__global__ __launch_bounds__(256) void abv_mfma_kernel(
    const unsigned short* __restrict__ f_bf, const unsigned short* __restrict__ xin_bf,
    const unsigned short* __restrict__ wA, const unsigned short* __restrict__ wB,
    const float* __restrict__ b1,
    unsigned short* __restrict__ A_bf, unsigned short* __restrict__ Bv_bf)
{
    const int tid = threadIdx.x;
    const int w = tid >> 6, l = tid & 63;
    const int lr = l & 15, lk = l >> 4;
    const int nb = blockIdx.x * 128 + w * 32;

    bf16x8 afr[2][5];
    #pragma unroll
    for (int rt = 0; rt < 2; ++rt) {
        int row = nb + rt * 16 + lr;
        #pragma unroll
        for (int ks = 0; ks < 4; ++ks)
            afr[rt][ks] = *reinterpret_cast<const bf16x8*>(f_bf + row * HID + ks * 32 + lk * 8);
        afr[rt][4] = *reinterpret_cast<const bf16x8*>(xin_bf + row * 32 + lk * 8);
    }

    #pragma unroll
    for (int pass = 0; pass < 2; ++pass) {
        const unsigned short* Wp = pass ? wB : wA;
        f32x4 acc[2][8];
        #pragma unroll
        for (int rt = 0; rt < 2; ++rt)
            #pragma unroll
            for (int cf = 0; cf < 8; ++cf)
                acc[rt][cf] = (f32x4){0.0f, 0.0f, 0.0f, 0.0f};
        #pragma unroll
        for (int cf = 0; cf < 8; ++cf) {
            const unsigned short* wrow = Wp + (cf * 16 + lr) * 160 + lk * 8;
            #pragma unroll
            for (int ks = 0; ks < 5; ++ks) {
                bf16x8 bfr = *reinterpret_cast<const bf16x8*>(wrow + ks * 32);
                acc[0][cf] = __builtin_amdgcn_mfma_f32_16x16x32_bf16(afr[0][ks], bfr, acc[0][cf], 0, 0, 0);
                acc[1][cf] = __builtin_amdgcn_mfma_f32_16x16x32_bf16(afr[1][ks], bfr, acc[1][cf], 0, 0, 0);
            }
        }
        unsigned short* Op = pass ? Bv_bf : A_bf;
        #pragma unroll
        for (int cf = 0; cf < 8; ++cf) {
            int col = cf * 16 + lr;
            float bb = pass ? 0.0f : b1[col];
            #pragma unroll
            for (int rt = 0; rt < 2; ++rt) {
                #pragma unroll
                for (int j = 0; j < 4; ++j) {
                    int row = nb + rt * 16 + lk * 4 + j;
                    Op[row * HID + col] = f2bf(acc[rt][cf][j] + bb);
                }
            }
        }
    }
}

// ---------------------------------------------------------------- fused edge kernel (CSR-sorted, bf16 gather, MFMA)
// LDS rows permuted so each lane's accumulators cover 8 CONSECUTIVE sorted edges.
__global__ __launch_bounds__(256) void edge_mfma_kernel(
    const int* __restrict__ src_s, const int* __restrict__ dst_s,
    const unsigned short* __restrict__ A_bf, const unsigned short* __restrict__ Bv_bf,
    const unsigned short* __restrict__ W2T, const float* __restrict__ b2,
    float* __restrict__ agg)
{
    __shared__ unsigned short t_bf[TILE_E * HID];   // 32 KB, XOR-swizzled rows
    const int tid = threadIdx.x;
    const int w = tid >> 6, l = tid & 63;
    const int lr = l & 15, lk = l >> 4;
    const int e0 = blockIdx.x * TILE_E;

    // gather + swish -> bf16 LDS (permuted rows): wave handles its own 32 edges
    #pragma unroll
    for (int i = 0; i < 8; ++i) {
        int un = l + i * 64;
        int e_loc = un >> 4, cb = un & 15;
        int e = e0 + w * 32 + e_loc;
        int dn = dst_s[e], sn = src_s[e];
        uint4 av = *reinterpret_cast<const uint4*>(A_bf + dn * HID + cb * 8);
        uint4 bv = *reinterpret_cast<const uint4*>(Bv_bf + sn * HID + cb * 8);
        auto proc = [](unsigned int aw, unsigned int bw) -> unsigned int {
            float a0 = __uint_as_float(aw << 16), a1 = __uint_as_float(aw & 0xffff0000u);
            float b0 = __uint_as_float(bw << 16), b1 = __uint_as_float(bw & 0xffff0000u);
            return pack2bf(swishf(a0 + b0), swishf(a1 + b1));
        };
        uint4 packed;
        packed.x = proc(av.x, bv.x);
        packed.y = proc(av.y, bv.y);
        packed.z = proc(av.z, bv.z);
        packed.w = proc(av.w, bv.w);
        // permutation: edge e_loc -> MFMA row mrow so lane lk owns edges lk*8..lk*8+7
        int mrow = ((e_loc >> 2) & 1) * 16 + (e_loc >> 3) * 4 + (e_loc & 3);
        int row = w * 32 + mrow;
        int byte = row * 256 + ((cb * 16) ^ ((mrow & 7) << 4));
        *reinterpret_cast<uint4*>(reinterpret_cast<char*>(t_bf) + byte) = packed;
    }
    // no barrier: each wave reads only rows it wrote

    bf16x8 afr[2][4];
    #pragma unroll
    for (int rt = 0; rt < 2; ++rt) {
        #pragma unroll
        for (int ks = 0; ks < 4; ++ks) {
            int r = w * 32 + rt * 16 + lr;
            int byte = r * 256 + ((lk * 16 + ks * 64) ^ ((r & 7) << 4));
            afr[rt][ks] = *reinterpret_cast<const bf16x8*>(reinterpret_cast<const char*>(t_bf) + byte);
        }
    }

    f32x4 acc[2][8];
    #pragma unroll
    for (int rt = 0; rt < 2; ++rt)
        #pragma unroll
        for (int cf = 0; cf < 8; ++cf)
            acc[rt][cf] = (f32x4){0.0f, 0.0f, 0.0f, 0.0f};

    #pragma unroll
    for (int cf = 0; cf < 8; ++cf) {
        const unsigned short* wrow = W2T + (cf * 16 + lr) * HID + lk * 8;
        #pragma unroll
        for (int ks = 0; ks < 4; ++ks) {
            bf16x8 bfr = *reinterpret_cast<const bf16x8*>(wrow + ks * 32);
            acc[0][cf] = __builtin_amdgcn_mfma_f32_16x16x32_bf16(afr[0][ks], bfr, acc[0][cf], 0, 0, 0);
            acc[1][cf] = __builtin_amdgcn_mfma_f32_16x16x32_bf16(afr[1][ks], bfr, acc[1][cf], 0, 0, 0);
        }
    }

    // epilogue: lane lk owns edges e0 + w*32 + lk*8 + m, m=0..7 (acc[m>>2][cf][m&3])
    const int ebase = e0 + w * 32 + lk * 8;
    int4 dA4 = *reinterpret_cast<const int4*>(dst_s + ebase);
    int4 dB4 = *reinterpret_cast<const int4*>(dst_s + ebase + 4);
    int d[8] = {dA4.x, dA4.y, dA4.z, dA4.w, dB4.x, dB4.y, dB4.z, dB4.w};
    #pragma unroll
    for (int cf = 0; cf < 8; ++cf) {
        int col = cf * 16 + lr;
        float bias = b2[col];
        float v[8];
        #pragma unroll
        for (int m = 0; m < 8; ++m) v[m] = swishf(acc[m >> 2][cf][m & 3] + bias);
        float run = v[0];
        int dp = d[0];
        #pragma unroll
        for (int m = 1; m < 8; ++m) {
            if (d[m] == dp) run += v[m];
            else { atomicAdd(&agg[dp * HID + col], run); run = v[m]; dp = d[m]; }
        }
        atomicAdd(&agg[dp * HID + col], run);
    }
}

// ---------------------------------------------------------------- update via MFMA + fused instance-norm stats
__global__ __launch_bounds__(256) void update_mfma_kernel(
    const unsigned short* __restrict__ f_bf, const float* __restrict__ agg,
    const int* __restrict__ cnt, const float* __restrict__ f32f,
    const float* __restrict__ tpos, const float* __restrict__ vars,
    const int* __restrict__ batch,
    const unsigned short* __restrict__ U1T, const float* __restrict__ u1tv,
    const float* __restrict__ b1, const unsigned short* __restrict__ U2T,
    const float* __restrict__ b2, float* __restrict__ h,
    float* __restrict__ dsum, float* __restrict__ dsq)
{
    __shared__ unsigned short q_lds[4 * 32 * HID];   // 32 KB, per-wave 8 KB regions
    const int tid = threadIdx.x;
    const int w = tid >> 6, l = tid & 63;
    const int lr = l & 15, lk = l >> 4;
    const int nb = blockIdx.x * 128 + w * 32;
    char* qbase = reinterpret_cast<char*>(q_lds) + w * 8192;

    float invd[2];
    #pragma unroll
    for (int rt = 0; rt < 2; ++rt) {
        int c = cnt[nb + rt * 16 + lr];
        invd[rt] = 1.0f / (float)(c > 0 ? c : 1);
    }

    f32x4 acc[2][8];
    #pragma unroll
    for (int rt = 0; rt < 2; ++rt)
        #pragma unroll
        for (int cf = 0; cf < 8; ++cf)
            acc[rt][cf] = (f32x4){0.0f, 0.0f, 0.0f, 0.0f};

    #pragma unroll
    for (int ks = 0; ks < 8; ++ks) {
        bf16x8 afr[2];
        #pragma unroll
        for (int rt = 0; rt < 2; ++rt) {
            int row = nb + rt * 16 + lr;
            if (ks < 4) {
                afr[rt] = *reinterpret_cast<const bf16x8*>(f_bf + row * HID + ks * 32 + lk * 8);
            } else {
                const float* ap = agg + row * HID + (ks - 4) * 32 + lk * 8;
                float4 a0 = *reinterpret_cast<const float4*>(ap);
                float4 a1 = *reinterpret_cast<const float4*>(ap + 4);
                float iv = invd[rt];
                union { bf16x8 v; unsigned int u[4]; } t;
                t.u[0] = pack2bf(a0.x * iv, a0.y * iv);
                t.u[1] = pack2bf(a0.z * iv, a0.w * iv);
                t.u[2] = pack2bf(a1.x * iv, a1.y * iv);
                t.u[3] = pack2bf(a1.z * iv, a1.w * iv);
                afr[rt] = t.v;
            }
        }
        #pragma unroll
        for (int cf = 0; cf < 8; ++cf) {
            bf16x8 bfr = *reinterpret_cast<const bf16x8*>(U1T + (cf * 16 + lr) * 256 + ks * 32 + lk * 8);
            acc[0][cf] = __builtin_amdgcn_mfma_f32_16x16x32_bf16(afr[0], bfr, acc[0][cf], 0, 0, 0);
            acc[1][cf] = __builtin_amdgcn_mfma_f32_16x16x32_bf16(afr[1], bfr, acc[1][cf], 0, 0, 0);
        }
    }

    // epilogue 1: add tv + bias, swish, write q to own LDS region (swizzled bf16)
    float tn[2][4], vn[2][4];
    #pragma unroll
    for (int rt = 0; rt < 2; ++rt)
        #pragma unroll
        for (int j = 0; j < 4; ++j) {
            int row = nb + rt * 16 + lk * 4 + j;
            tn[rt][j] = tpos[row] * 0.25f;
            vn[rt][j] = vars[row];
        }
    #pragma unroll
    for (int cf = 0; cf < 8; ++cf) {
        int col = cf * 16 + lr;
        float bb = b1[col], wt = u1tv[col], wv = u1tv[HID + col];
        #pragma unroll
        for (int rt = 0; rt < 2; ++rt)
            #pragma unroll
            for (int j = 0; j < 4; ++j) {
                float qv = swishf(acc[rt][cf][j] + bb + tn[rt][j] * wt + vn[rt][j] * wv);
                int rloc = rt * 16 + lk * 4 + j;
                *reinterpret_cast<unsigned short*>(qbase + rloc * 256 + ((col * 2) ^ ((rloc & 7) << 4))) = f2bf(qv);
            }
    }
    // no barrier: wave reads only its own region

    f32x4 acc2[2][8];
    #pragma unroll
    for (int rt = 0; rt < 2; ++rt)
        #pragma unroll
        for (int cf = 0; cf < 8; ++cf)
            acc2[rt][cf] = (f32x4){0.0f, 0.0f, 0.0f, 0.0f};

    #pragma unroll
    for (int ks = 0; ks < 4; ++ks) {
        bf16x8 afr[2];
        #pragma unroll
        for (int rt = 0; rt < 2; ++rt) {
            int rloc = rt * 16 + lr;
            afr[rt] = *reinterpret_cast<const bf16x8*>(qbase + rloc * 256 + ((ks * 64 + lk * 16) ^ ((rloc & 7) << 4)));
        }
        #pragma unroll
        for (int cf = 0; cf < 8; ++cf) {
            bf16x8 bfr = *reinterpret_cast<const bf16x8*>(U2T + (cf * 16 + lr) * HID + ks * 32 + lk * 8);
            acc2[0][cf] = __builtin_amdgcn_mfma_f32_16x16x32_bf16(afr[0], bfr, acc2[0][cf], 0, 0, 0);
            acc2[1][cf] = __builtin_amdgcn_mfma_f32_16x16x32_bf16(afr[1], bfr, acc2[1][cf], 0, 0, 0);
        }
    }

    // epilogue 2: h = f + swish(acc2 + b2), fused per-graph stats
    const int bfirst = batch[nb];
    const bool uni = (bfirst == batch[nb + 31]);
    #pragma unroll
    for (int cf = 0; cf < 8; ++cf) {
        int col = cf * 16 + lr;
        float bb = b2[col];
        float s = 0.0f, s2 = 0.0f;
        #pragma unroll
        for (int rt = 0; rt < 2; ++rt)
            #pragma unroll
            for (int j = 0; j < 4; ++j) {
                int row = nb + rt * 16 + lk * 4 + j;
                float hv = f32f[row * HID + col] + swishf(acc2[rt][cf][j] + bb);
                h[row * HID + col] = hv;
                if (uni) { s += hv; s2 += hv * hv; }
                else {
                    int b = batch[row];
                    atomicAdd(&dsum[b * HID + col], hv);
                    atomicAdd(&dsq[b * HID + col], hv * hv);
                }
            }
        if (uni) {
            s += __shfl_xor(s, 16); s += __shfl_xor(s, 32);
            s2 += __shfl_xor(s2, 16); s2 += __shfl_xor(s2, 32);
            if (lk == 0) {
                atomicAdd(&dsum[bfirst * HID + col], s);
                atomicAdd(&dsq[bfirst * HID + col], s2);
            }
        }
    }
}

// ---------------------------------------------------------------- normalize (writes f32 + bf16)
__global__ __launch_bounds__(256) void norm_kernel(
    const float* __restrict__ h, const int* __restrict__ batch,
    const float* __restrict__ dsum, const float* __restrict__ dsq,
    const float* __restrict__ gcount, float* __restrict__ f,
    unsigned short* __restrict__ f_bf)
{
    const int gid = blockIdx.x * 256 + threadIdx.x;   // N*16
    const int n = gid >> 4, c0 = (gid & 15) * 8;
    const int b = batch[n];
    const float inv = 1.0f / gcount[b];
    float4 h0 = *reinterpret_cast<const float4*>(h + n * HID + c0);
    float4 h1 = *reinterpret_cast<const float4*>(h + n * HID + c0 + 4);
    float o[8];
    #pragma unroll
    for (int i = 0; i < 8; ++i) {
        float hx = (i < 4) ? reinterpret_cast<const float*>(&h0)[i] : reinterpret_cast<const float*>(&h1)[i - 4];
        float mean = dsum[b * HID + c0 + i] * inv;
        float var = dsq[b * HID + c0 + i] * inv - mean * mean;
        o[i] = (hx - mean) * rsqrtf(var + EPSF);
    }
    float4 o0 = {o[0], o[1], o[2], o[3]};
    float4 o1 = {o[4], o[5], o[6], o[7]};
    *reinterpret_cast<float4*>(f + n * HID + c0) = o0;
    *reinterpret_cast<float4*>(f + n * HID + c0 + 4) = o1;
    uint4 pb;
    pb.x = pack2bf(o[0], o[1]);
    pb.y = pack2bf(o[2], o[3]);
    pb.z = pack2bf(o[4], o[5]);
    pb.w = pack2bf(o[6], o[7]);
    *reinterpret_cast<uint4*>(f_bf + n * HID + c0) = pb;
}

// ---------------------------------------------------------------- conv head
__global__ __launch_bounds__(256) void head_kernel(
    const float* __restrict__ f, const float* __restrict__ u,
    const float* __restrict__ c1w, const float* __restrict__ c1b,
    const float* __restrict__ c2w, const float* __restrict__ c2b,
    float* __restrict__ out)
{
    __shared__ float fs[16][HID];
    __shared__ float y1[16][8][40];
    const int tid = threadIdx.x;
    const int n0 = blockIdx.x * 16;
    #pragma unroll
    for (int i = 0; i < 2; ++i) {
        int qi = tid + i * 256;
        int node = qi >> 5, kq = qi & 31;
        *reinterpret_cast<float4*>(&fs[node][kq * 4]) =
            *reinterpret_cast<const float4*>(f + (n0 + node) * HID + kq * 4);
    }
    __syncthreads();
    {
        const int node = tid >> 4;
        const int rem = tid & 15;
        const int o = rem >> 1;
        const int ph = rem & 1;
        const float cb = c1b[o];
        float wk[16];
        #pragma unroll
        for (int k = 0; k < 16; ++k) wk[k] = c1w[o * 16 + k];
        for (int p = ph * 19; p < ph * 19 + 19; ++p) {
            float acc = cb;
            #pragma unroll
            for (int k = 0; k < 16; ++k) acc += fs[node][p * 3 + k] * wk[k];
            y1[node][o][p] = swishf(acc);
        }
    }
    __syncthreads();
    const float cb2 = c2b[0];
    #pragma unroll
    for (int pass = 0; pass < 2; ++pass) {
        int unit = tid + pass * 256;
        if (unit < 16 * TW) {
            int node = unit / TW, t = unit % TW;
            float acc = cb2;
            #pragma unroll
            for (int o = 0; o < 8; ++o)
                #pragma unroll
                for (int k = 0; k < 14; ++k)
                    acc += y1[node][o][t + k] * c2w[o * 14 + k];
            int n = n0 + node;
            out[n * TW + t] = u[n * TW + (TW - 1)] + (0.016f * (float)(t + 1)) * acc;
        }
    }
}

// ---------------------------------------------------------------- launch
extern "C" void kernel_launch(void* const* d_in, const int* in_sizes, int n_in,
                              void* d_out, int out_size, void* d_ws, size_t ws_size,
                              hipStream_t stream)
{
    (void)in_sizes; (void)n_in; (void)out_size; (void)ws_size;
    const float* u      = (const float*)d_in[0];
    const float* xpos   = (const float*)d_in[1];
    const float* tpos   = (const float*)d_in[2];
    const float* vars   = (const float*)d_in[3];
    const int*   ei     = (const int*)d_in[4];
    const int*   batch  = (const int*)d_in[5];
    const float* emb_w1 = (const float*)d_in[6];
    const float* emb_b1 = (const float*)d_in[7];
    const float* emb_w2 = (const float*)d_in[8];
    const float* emb_b2 = (const float*)d_in[9];
    const float* m1_w   = (const float*)d_in[10];
    const float* m1_b   = (const float*)d_in[11];
    const float* m2_w   = (const float*)d_in[12];
    const float* m2_b   = (const float*)d_in[13];
    const float* u1_w   = (const float*)d_in[14];
    const float* u1_b   = (const float*)d_in[15];
    const float* u2_w   = (const float*)d_in[16];
    const float* u2_b   = (const float*)d_in[17];
    const float* c1w    = (const float*)d_in[18];
    const float* c1b    = (const float*)d_in[19];
    const float* c2w    = (const float*)d_in[20];
    const float* c2b    = (const float*)d_in[21];
    float* out = (float*)d_out;

    char* ws = (char*)d_ws;
    const size_t fbytes = (size_t)N_NODES * HID * sizeof(float);
    float* f      = (float*)(ws);
    float* h      = (float*)(ws + fbytes);
    float* agg    = (float*)(ws + 2 * fbytes);
    char*  p      = ws + 3 * fbytes;
    unsigned short* A_bf   = (unsigned short*)p;  p += (size_t)N_NODES * HID * 2;
    unsigned short* Bv_bf  = (unsigned short*)p;  p += (size_t)N_NODES * HID * 2;
    unsigned short* f_bf   = (unsigned short*)p;  p += (size_t)N_NODES * HID * 2;
    unsigned short* xin_bf = (unsigned short*)p;  p += (size_t)N_NODES * 32 * 2;
    int* cnt      = (int*)p;               p += (size_t)N_NODES * 4;
    int* cursor   = (int*)p;               p += (size_t)N_NODES * 4;
    int* src_s    = (int*)p;               p += (size_t)N_EDGES * 4;
    int* dst_s    = (int*)p;               p += (size_t)N_EDGES * 4;
    int* bsum     = (int*)p;               p += 256 * 4;
    int* bpref    = (int*)p;               p += 256 * 4;
    float* dsum   = (float*)p;             p += BGRAPH * HID * 4;
    float* dsq    = (float*)p;             p += BGRAPH * HID * 4;
    float* gcount = (float*)p;             p += BGRAPH * 4;
    unsigned short* W2T = (unsigned short*)p;  p += (size_t)LAYERS * HID * HID * 2;
    unsigned short* wAB = (unsigned short*)p;  p += (size_t)LAYERS * 2 * 128 * 160 * 2;
    unsigned short* U1T = (unsigned short*)p;  p += (size_t)LAYERS * 128 * 256 * 2;
    unsigned short* U2T = (unsigned short*)p;  p += (size_t)LAYERS * 128 * 128 * 2;

    // CSR build
    hipMemsetAsync(cnt, 0, (size_t)N_NODES * 4, stream);
    count_kernel<<<N_EDGES / 256, 256, 0, stream>>>(ei, cnt);
    block_sum_kernel<<<N_NODES / 256, 256, 0, stream>>>(cnt, bsum);
    scan_bsum_kernel<<<1, 256, 0, stream>>>(bsum, bpref);
    offsets_kernel<<<N_NODES / 256, 256, 0, stream>>>(cnt, bpref, cursor);
    scatter_kernel<<<N_EDGES / 256, 256, 0, stream>>>(ei, cursor, src_s, dst_s);

    // weight / input prep
    w2bf_kernel<<<LAYERS * HID * HID / 256, 256, 0, stream>>>(m2_w, W2T);
    w1t_kernel<<<LAYERS * 2 * 128 * 160 / 256, 256, 0, stream>>>(m1_w, wAB);
    u1t_kernel<<<LAYERS * 128 * 256 / 256, 256, 0, stream>>>(u1_w, U1T);
    u2t_kernel<<<LAYERS * 128 * 128 / 256, 256, 0, stream>>>(u2_w, U2T);
    xin_kernel<<<N_NODES * 32 / 256, 256, 0, stream>>>(u, xpos, tpos, vars, xin_bf);
    gcount_kernel<<<1, 64, 0, stream>>>(batch, gcount);
    emb_kernel<<<N_NODES / NB, 128, 0, stream>>>(u, xpos, tpos, vars,
                                                 emb_w1, emb_b1, emb_w2, emb_b2, f, f_bf);

    for (int l = 0; l < LAYERS; ++l) {
        abv_mfma_kernel<<<N_NODES / 128, 256, 0, stream>>>(
            f_bf, xin_bf,
            wAB + (size_t)l * 2 * 128 * 160,
            wAB + (size_t)l * 2 * 128 * 160 + 128 * 160,
            m1_b + (size_t)l * HID, A_bf, Bv_bf);
        hipMemsetAsync(agg, 0, fbytes, stream);
        edge_mfma_kernel<<<N_EDGES / TILE_E, 256, 0, stream>>>(
            src_s, dst_s, A_bf, Bv_bf, W2T + (size_t)l * HID * HID,
            m2_b + (size_t)l * HID, agg);
        hipMemsetAsync(dsum, 0, (size_t)2 * BGRAPH * HID * 4, stream);
        update_mfma_kernel<<<N_NODES / 128, 256, 0, stream>>>(
            f_bf, agg, cnt, f, tpos, vars, batch,
            U1T + (size_t)l * 128 * 256,
            u1_w + (size_t)l * 258 * 128 + 256 * 128,
            u1_b + (size_t)l * HID,
            U2T + (size_t)l * 128 * 128,
            u2_b + (size_t)l * HID, h, dsum, dsq);
        norm_kernel<<<N_NODES * 16 / 256, 256, 0, stream>>>(
            h, batch, dsum, dsq, gcount, f, f_bf);
    }
    head_kernel<<<N_NODES / 16, 256, 0, stream>>>(f, u, c1w, c1b, c2w, c2b, out);
}